// Round 4
// baseline (16050.302 us; speedup 1.0000x reference)
//
#include <hip/hip_runtime.h>

// ---------------- problem constants ----------------
static constexpr int B  = 4;
static constexpr int N0 = 2048;
static constexpr int LF = 8;
static constexpr int M1 = 1024, M2 = 512, M3 = 256;
static constexpr int O1 = 64, O2 = 128, O3 = 256;
static constexpr int NS1 = 12, NS2 = 8, NS3 = 4, NSQ = 4;
static constexpr int C1 = 67, C2 = 195, C3 = 387;

// Exact float32 squared distance in numpy's op order ((dx^2+dy^2)+dz^2),
// with _rn intrinsics to forbid FMA contraction (discrete decisions depend on it).
__device__ __forceinline__ float sq3(float ax, float ay, float az,
                                     float bx, float by, float bz) {
  float dx = __fsub_rn(ax, bx), dy = __fsub_rn(ay, by), dz = __fsub_rn(az, bz);
  return __fadd_rn(__fadd_rn(__fmul_rn(dx, dx), __fmul_rn(dy, dy)),
                   __fmul_rn(dz, dz));
}

template <int CTRL>
__device__ __forceinline__ unsigned dpp_u(unsigned v) {
  return (unsigned)__builtin_amdgcn_update_dpp((int)v, (int)v, CTRL, 0xf, 0xf, false);
}
template <int CTRL>
__device__ __forceinline__ float dpp_f(float v) {
  return __uint_as_float(dpp_u<CTRL>(__float_as_uint(v)));
}

// One DPP reduce step on the 5-tuple (hi=dist bits, lo=0x7FFFFFFF-idx, x, y, z).
// Self-fallback (old=self) is harmless: max-combine is idempotent.
template <int CTRL>
__device__ __forceinline__ void dpp_step(unsigned& hi, unsigned& lo,
                                         float& x, float& y, float& z) {
  const unsigned ohi = dpp_u<CTRL>(hi);
  const unsigned olo = dpp_u<CTRL>(lo);
  const float ox = dpp_f<CTRL>(x), oy = dpp_f<CTRL>(y), oz = dpp_f<CTRL>(z);
  const bool take = (ohi > hi) || (ohi == hi && olo > lo);
  hi = take ? ohi : hi;
  lo = take ? olo : lo;
  x = take ? ox : x;
  y = take ? oy : y;
  z = take ? oz : z;
}

// ---------------- furthest point sampling (register-resident, coord-carrying) ----
// One block (256 thr = 4 waves) per batch; __launch_bounds__(256,1) gives the
// register allocator headroom so ppx/ppy/ppz/dist stay in VGPRs (round-3 profile
// showed VGPR=40/20 => compiler demoted the arrays; that was the 2x gap).
// Winner COORDS travel with the key through the DPP reduce, so no LDS point
// array and no index->coords lookup. One parity-double-buffered barrier/iter.
// Tie-break = first occurrence (min idx) via lo = 0x7FFFFFFF - idx, matching
// jnp.argmax bit-exactly.
template <int N>
__global__ __launch_bounds__(256, 1) void fps_dpp(const float* __restrict__ pts,
                                                  long bstride, int npoint,
                                                  float* __restrict__ out) {
  constexpr int K = N / 256;
  const int b = blockIdx.x;
  const float* p = pts + (long)b * bstride;
  const int tid = threadIdx.x;
  const int lane = tid & 63;
  const int wid = tid >> 6;
  __shared__ unsigned wb[2][4][8];  // [parity][wave][hi,lo,x,y,z,pad...]
  float ppx[K], ppy[K], ppz[K], dist[K];
#pragma unroll
  for (int k = 0; k < K; ++k) {
    const int j = tid * K + k;
    ppx[k] = p[3 * j + 0];
    ppy[k] = p[3 * j + 1];
    ppz[k] = p[3 * j + 2];
    dist[k] = 1e10f;
  }
  float lx = p[0], ly = p[1], lz = p[2];  // first selected point = index 0
  float* outb = out + (long)b * npoint * 3;
  const unsigned base = 0x7FFFFFFFu - (unsigned)(tid * K);
  for (int i = 0; i < npoint; ++i) {
    if (tid == 0) {
      outb[3 * i + 0] = lx; outb[3 * i + 1] = ly; outb[3 * i + 2] = lz;
    }
    // local (per-lane) argmax over K owned points; strict '>' keeps smallest k
    unsigned bhi = 0u, blo = base;
    float bx = ppx[0], by = ppy[0], bz = ppz[0];
#pragma unroll
    for (int k = 0; k < K; ++k) {
      const float d = sq3(ppx[k], ppy[k], ppz[k], lx, ly, lz);
      const float dm = fminf(dist[k], d);
      dist[k] = dm;
      const unsigned h = __float_as_uint(dm);
      const bool take = h > bhi;
      bhi = take ? h : bhi;
      blo = take ? (base - (unsigned)k) : blo;
      bx = take ? ppx[k] : bx;
      by = take ? ppy[k] : by;
      bz = take ? ppz[k] : bz;
    }
    // wave64 reduce on the VALU pipe; winner lands in lane 63
    dpp_step<0x111>(bhi, blo, bx, by, bz);  // row_shr:1
    dpp_step<0x112>(bhi, blo, bx, by, bz);  // row_shr:2
    dpp_step<0x114>(bhi, blo, bx, by, bz);  // row_shr:4
    dpp_step<0x118>(bhi, blo, bx, by, bz);  // row_shr:8
    dpp_step<0x142>(bhi, blo, bx, by, bz);  // row_bcast15
    dpp_step<0x143>(bhi, blo, bx, by, bz);  // row_bcast31
    if (lane == 63) {
      unsigned* e = wb[i & 1][wid];
      e[0] = bhi; e[1] = blo;
      e[2] = __float_as_uint(bx); e[3] = __float_as_uint(by); e[4] = __float_as_uint(bz);
    }
    __syncthreads();
    unsigned ghi = 0u, glo = 0u;
    float gx = 0.f, gy = 0.f, gz = 0.f;
#pragma unroll
    for (int w = 0; w < 4; ++w) {
      const unsigned* e = wb[i & 1][w];
      const unsigned ehi = e[0], elo = e[1];
      const bool take = (ehi > ghi) || (ehi == ghi && elo > glo);
      ghi = take ? ehi : ghi;
      glo = take ? elo : glo;
      gx = take ? __uint_as_float(e[2]) : gx;
      gy = take ? __uint_as_float(e[3]) : gy;
      gz = take ? __uint_as_float(e[4]) : gz;
    }
    lx = gx; ly = gy; lz = gz;
  }
}

// ---------------- ball query ----------------
// First ns in-range indices in ascending order; pad with first; 0 if none.
__global__ __launch_bounds__(256) void bq_kernel(const float* __restrict__ nxyz,
                                                 const float* __restrict__ sxyz,
                                                 float r2, int ns, int M, int Ns,
                                                 int* __restrict__ idx, int total) {
  int t = blockIdx.x * 256 + threadIdx.x;
  if (t >= total) return;
  int b = t / M;
  const float* q = nxyz + (long)t * 3;
  const float qx = q[0], qy = q[1], qz = q[2];
  const float* s = sxyz + (long)b * Ns * 3;
  int* o = idx + (long)t * ns;
  int cnt = 0;
  for (int j = 0; j < Ns; ++j) {
    float d2 = sq3(qx, qy, qz, s[3 * j], s[3 * j + 1], s[3 * j + 2]);
    if (d2 < r2) {
      o[cnt++] = j;
      if (cnt == ns) break;
    }
  }
  int fill = (cnt > 0) ? o[0] : 0;
  for (int k = cnt; k < ns; ++k) o[k] = fill;
}

// ---------------- point-rnn cell: S_out = max_s W @ [S2g; X1; disp] ----------------
// One block per (b,m), blockDim == O (one thread per output channel).
// corr stored transposed [C][NS]: staging writes contiguous, compute reads are
// wave-broadcast. Dot product c-outer/s-inner with accs[NS] in registers =>
// each W element loaded once (was NS times).
template <int NS>
__global__ void cell_kernel(const float* __restrict__ P1, const float* __restrict__ X1,
                            const float* __restrict__ P2, const float* __restrict__ S2,
                            const int* __restrict__ idx, const float* __restrict__ W,
                            float* __restrict__ Sout, int M, int Cin, int O) {
  const int C = O + Cin + 3;
  const int bm = blockIdx.x;
  const int b = bm / M, m = bm - b * M;
  extern __shared__ float corrT[];  // [C][NS]
  const int* id = idx + (long)bm * NS;
  const float p1x = P1[bm * 3 + 0], p1y = P1[bm * 3 + 1], p1z = P1[bm * 3 + 2];
  for (int e = threadIdx.x; e < C * NS; e += blockDim.x) {
    const int c = e / NS, s = e - c * NS;
    const int j = id[s];
    float v;
    if (c < O) {
      v = S2[((long)b * O + c) * M + j];
    } else if (c < O + Cin) {
      v = X1[((long)b * Cin + (c - O)) * M + m];
    } else {
      const int d = c - O - Cin;
      const float pj = P2[((long)b * M + j) * 3 + d];
      const float pm = (d == 0) ? p1x : ((d == 1) ? p1y : p1z);
      v = __fsub_rn(pj, pm);
    }
    corrT[e] = v;
  }
  __syncthreads();
  const int o = threadIdx.x;
  const float* w = W + (long)o * C;
  float accs[NS];
#pragma unroll
  for (int s = 0; s < NS; ++s) accs[s] = 0.f;
  for (int c = 0; c < C; ++c) {
    const float wc = w[c];
    const float* cs = corrT + c * NS;
#pragma unroll
    for (int s = 0; s < NS; ++s) accs[s] = fmaf(wc, cs[s], accs[s]);
  }
  float best = accs[0];
#pragma unroll
  for (int s = 1; s < NS; ++s) best = fmaxf(best, accs[s]);
  Sout[((long)b * O + o) * M + m] = best;
}

// ---------------- grouped feature max ----------------
__global__ __launch_bounds__(256) void gmax_kernel(const float* __restrict__ feat,
                                                   const int* __restrict__ idx,
                                                   float* __restrict__ out, int Cc,
                                                   int M, int Ms, int ns, int total) {
  int t = blockIdx.x * 256 + threadIdx.x;
  if (t >= total) return;
  int m = t % M;
  int bc = t / M;
  int b = bc / Cc;
  const int* id = idx + ((long)b * M + m) * ns;
  const float* f = feat + (long)bc * Ms;
  float best = -3.0e38f;
  for (int s = 0; s < ns; ++s) best = fmaxf(best, f[id[s]]);
  out[t] = best;
}

// ---------------- 3-NN + inverse-distance weights ----------------
// Strict '<' insertion matches lax.top_k tie semantics (lower index first).
__global__ __launch_bounds__(256) void knn3_kernel(const float* __restrict__ unk,
                                                   long ubstride, int Mu,
                                                   const float* __restrict__ kn, int Mk,
                                                   int* __restrict__ oi,
                                                   float* __restrict__ ow, int total) {
  int t = blockIdx.x * 256 + threadIdx.x;
  if (t >= total) return;
  int b = t / Mu, m = t - b * Mu;
  const float* q = unk + (long)b * ubstride + (long)m * 3;
  const float qx = q[0], qy = q[1], qz = q[2];
  const float* s = kn + (long)b * Mk * 3;
  float d0 = 3e38f, d1 = 3e38f, d2v = 3e38f;
  int i0 = 0, i1 = 0, i2 = 0;
  for (int j = 0; j < Mk; ++j) {
    float dd = sq3(qx, qy, qz, s[3 * j], s[3 * j + 1], s[3 * j + 2]);
    if (dd < d0) {
      d2v = d1; i2 = i1; d1 = d0; i1 = i0; d0 = dd; i0 = j;
    } else if (dd < d1) {
      d2v = d1; i2 = i1; d1 = dd; i1 = j;
    } else if (dd < d2v) {
      d2v = dd; i2 = j;
    }
  }
  float r0 = 1.0f / __fadd_rn(d0, 1e-8f);
  float r1 = 1.0f / __fadd_rn(d1, 1e-8f);
  float r2 = 1.0f / __fadd_rn(d2v, 1e-8f);
  float sum = __fadd_rn(__fadd_rn(r0, r1), r2);
  ow[t * 3 + 0] = r0 / sum;
  ow[t * 3 + 1] = r1 / sum;
  ow[t * 3 + 2] = r2 / sum;
  oi[t * 3 + 0] = i0;
  oi[t * 3 + 1] = i1;
  oi[t * 3 + 2] = i2;
}

// ---------------- weighted 3-gather (interp) into concat region ----------------
__global__ __launch_bounds__(256) void interp_kernel(const float* __restrict__ f,
                                                     const int* __restrict__ ii,
                                                     const float* __restrict__ iw,
                                                     float* __restrict__ out, int Cc,
                                                     int Coff, int Ctot, int Ms, int Md,
                                                     int total) {
  int t = blockIdx.x * 256 + threadIdx.x;
  if (t >= total) return;
  int m = t % Md;
  int bc = t / Md;
  int c = bc % Cc;
  int b = bc / Cc;
  const int* id = ii + ((long)b * Md + m) * 3;
  const float* w = iw + ((long)b * Md + m) * 3;
  const float* fb = f + ((long)b * Cc + c) * Ms;
  float v = __fadd_rn(__fadd_rn(__fmul_rn(fb[id[0]], w[0]), __fmul_rn(fb[id[1]], w[1])),
                      __fmul_rn(fb[id[2]], w[2]));
  out[((long)b * Ctot + Coff + c) * Md + m] = v;
}

__global__ __launch_bounds__(256) void copyrows_kernel(const float* __restrict__ f,
                                                       float* __restrict__ out, int Cc,
                                                       int Coff, int Ctot, int M,
                                                       int total) {
  int t = blockIdx.x * 256 + threadIdx.x;
  if (t >= total) return;
  int m = t % M;
  int bc = t / M;
  int c = bc % Cc;
  int b = bc / Cc;
  out[((long)b * Ctot + Coff + c) * M + m] = f[t];
}

__global__ __launch_bounds__(256) void copyframe_kernel(const float* __restrict__ xyzs,
                                                        float* __restrict__ frame,
                                                        int total) {
  int t = blockIdx.x * 256 + threadIdx.x;
  if (t >= total) return;
  int b = t / (N0 * 3);
  int rr = t - b * (N0 * 3);
  frame[t] = xyzs[((long)b * LF + (LF / 2 - 1)) * (N0 * 3) + rr];
}

// ---------------- fused interp-to-l1 + 2-layer MLP + frame update ----------------
__global__ __launch_bounds__(64) void mlp_kernel(const float* __restrict__ l2,
                                                 const int* __restrict__ ii,
                                                 const float* __restrict__ iw,
                                                 const float* __restrict__ W1,
                                                 const float* __restrict__ b1,
                                                 const float* __restrict__ W2,
                                                 const float* __restrict__ b2,
                                                 float* __restrict__ frame,
                                                 float* __restrict__ out, int td) {
  const int bn = blockIdx.x;
  const int b = bn / N0, n = bn - b * N0;
  __shared__ float col[448];
  __shared__ float h[64];
  const int* id = ii + (long)bn * 3;
  const float* w = iw + (long)bn * 3;
  const float w0 = w[0], w1 = w[1], w2v = w[2];
  const int i0 = id[0], i1 = id[1], i2 = id[2];
  const float* l2b = l2 + (long)b * 448 * M1;
  for (int c = threadIdx.x; c < 448; c += 64) {
    const float* r = l2b + (long)c * M1;
    col[c] = __fadd_rn(__fadd_rn(__fmul_rn(r[i0], w0), __fmul_rn(r[i1], w1)),
                       __fmul_rn(r[i2], w2v));
  }
  __syncthreads();
  const int o = threadIdx.x;
  const float* wr = W1 + (long)o * 448;
  float acc = b1[o];
  for (int c = 0; c < 448; ++c) acc = fmaf(wr[c], col[c], acc);
  h[o] = fmaxf(acc, 0.0f);
  __syncthreads();
  if (o < 3) {
    const float* w2r = W2 + o * 64;
    float acc2 = b2[o];
    for (int c = 0; c < 64; ++c) acc2 = fmaf(w2r[c], h[c], acc2);
    float nf = frame[(long)bn * 3 + o] + acc2;
    frame[(long)bn * 3 + o] = nf;
    out[(((long)b * 4 + td) * N0 + n) * 3 + o] = nf;
  }
}

extern "C" void kernel_launch(void* const* d_in, const int* in_sizes, int n_in,
                              void* d_out, int out_size, void* d_ws, size_t ws_size,
                              hipStream_t stream) {
  const float* xyzs = (const float*)d_in[0];
  const float* enw[3] = {(const float*)d_in[1], (const float*)d_in[2], (const float*)d_in[3]};
  const float* dew[3] = {(const float*)d_in[4], (const float*)d_in[5], (const float*)d_in[6]};
  const float* mw1 = (const float*)d_in[7];
  const float* mb1 = (const float*)d_in[8];
  const float* mw2 = (const float*)d_in[9];
  const float* mb2 = (const float*)d_in[10];
  float* out = (float*)d_out;

  float* ws = (float*)d_ws;
  size_t off = 0;
  auto alloc = [&](size_t nn) { float* p = ws + off; off += nn; return p; };
  float* frame = alloc((size_t)B * N0 * 3);
  float* xyz1b[2] = {alloc((size_t)B * M1 * 3), alloc((size_t)B * M1 * 3)};
  float* xyz2b[2] = {alloc((size_t)B * M2 * 3), alloc((size_t)B * M2 * 3)};
  float* xyz3b[2] = {alloc((size_t)B * M3 * 3), alloc((size_t)B * M3 * 3)};
  float* S1bf[2] = {alloc((size_t)B * O1 * M1), alloc((size_t)B * O1 * M1)};
  float* S2bf[2] = {alloc((size_t)B * O2 * M2), alloc((size_t)B * O2 * M2)};
  float* S3bf[2] = {alloc((size_t)B * O3 * M3), alloc((size_t)B * O3 * M3)};
  float* feat2 = alloc((size_t)B * O1 * M2);
  float* feat3 = alloc((size_t)B * O2 * M3);
  float* l3 = alloc((size_t)B * 384 * M2);
  float* l2 = alloc((size_t)B * 448 * M1);
  float* iw = alloc((size_t)B * N0 * 3);
  int* ii = (int*)alloc((size_t)B * N0 * 3);
  int* idxc = (int*)alloc((size_t)B * M1 * NS1);
  int* idxq = (int*)alloc((size_t)B * M2 * NSQ);

  // zero-init the t=0 "previous state" buffers (ping index 1)
  hipMemsetAsync(xyz1b[1], 0, (size_t)B * M1 * 3 * 4, stream);
  hipMemsetAsync(xyz2b[1], 0, (size_t)B * M2 * 3 * 4, stream);
  hipMemsetAsync(xyz3b[1], 0, (size_t)B * M3 * 3 * 4, stream);
  hipMemsetAsync(S1bf[1], 0, (size_t)B * O1 * M1 * 4, stream);
  hipMemsetAsync(S2bf[1], 0, (size_t)B * O2 * M2 * 4, stream);
  hipMemsetAsync(S3bf[1], 0, (size_t)B * O3 * M3 * 4, stream);

  double r;
  r = 4.0 + 1e-6;         const float r2c1 = (float)(r * r);
  r = 2.0 * 4.0 / 4.0 + 1e-6; const float r2q2 = (float)(r * r);
  r = 2.0 * 4.0 + 1e-6;   const float r2c2 = (float)(r * r);
  r = 4.0 * 4.0 / 4.0 + 1e-6; const float r2q3 = (float)(r * r);
  r = 3.0 * 4.0 + 1e-6;   const float r2c3 = (float)(r * r);

  auto grid = [](int total) { return dim3((unsigned)((total + 255) / 256)); };

  int cur = 0;
  for (int t = 0; t < LF; ++t) {
    const bool enc = t < LF / 2;
    const float* W1 = enc ? enw[0] : dew[0];
    const float* W2 = enc ? enw[1] : dew[1];
    const float* W3 = enc ? enw[2] : dew[2];
    const float* fp;
    long fstr;
    if (enc) {
      fp = xyzs + (long)t * N0 * 3;
      fstr = (long)LF * N0 * 3;
    } else {
      if (t == LF / 2)
        copyframe_kernel<<<grid(B * N0 * 3), 256, 0, stream>>>(xyzs, frame, B * N0 * 3);
      fp = frame;
      fstr = (long)N0 * 3;
    }
    const int prev = 1 - cur;

    // ---- level 1 ----
    fps_dpp<2048><<<B, 256, 0, stream>>>(fp, fstr, M1, xyz1b[cur]);
    bq_kernel<<<grid(B * M1), 256, 0, stream>>>(xyz1b[cur], xyz1b[prev], r2c1, NS1, M1, M1,
                                                idxc, B * M1);
    cell_kernel<NS1><<<B * M1, O1, C1 * NS1 * 4, stream>>>(xyz1b[cur], nullptr, xyz1b[prev],
                                                           S1bf[prev], idxc, W1, S1bf[cur],
                                                           M1, 0, O1);
    // ---- level 2 ----
    fps_dpp<1024><<<B, 256, 0, stream>>>(xyz1b[cur], (long)M1 * 3, M2, xyz2b[cur]);
    bq_kernel<<<grid(B * M2), 256, 0, stream>>>(xyz2b[cur], xyz1b[cur], r2q2, NSQ, M2, M1,
                                                idxq, B * M2);
    gmax_kernel<<<grid(B * O1 * M2), 256, 0, stream>>>(S1bf[cur], idxq, feat2, O1, M2, M1,
                                                       NSQ, B * O1 * M2);
    bq_kernel<<<grid(B * M2), 256, 0, stream>>>(xyz2b[cur], xyz2b[prev], r2c2, NS2, M2, M2,
                                                idxc, B * M2);
    cell_kernel<NS2><<<B * M2, O2, C2 * NS2 * 4, stream>>>(xyz2b[cur], feat2, xyz2b[prev],
                                                           S2bf[prev], idxc, W2, S2bf[cur],
                                                           M2, O1, O2);
    // ---- level 3 ----
    fps_dpp<512><<<B, 256, 0, stream>>>(xyz2b[cur], (long)M2 * 3, M3, xyz3b[cur]);
    bq_kernel<<<grid(B * M3), 256, 0, stream>>>(xyz3b[cur], xyz2b[cur], r2q3, NSQ, M3, M2,
                                                idxq, B * M3);
    gmax_kernel<<<grid(B * O2 * M3), 256, 0, stream>>>(S2bf[cur], idxq, feat3, O2, M3, M2,
                                                       NSQ, B * O2 * M3);
    bq_kernel<<<grid(B * M3), 256, 0, stream>>>(xyz3b[cur], xyz3b[prev], r2c3, NS3, M3, M3,
                                                idxc, B * M3);
    cell_kernel<NS3><<<B * M3, O3, C3 * NS3 * 4, stream>>>(xyz3b[cur], feat3, xyz3b[prev],
                                                           S3bf[prev], idxc, W3, S3bf[cur],
                                                           M3, O2, O3);

    if (!enc) {
      const int td = t - LF / 2;
      // l3 = concat([interp(p2<-p3, f3), f2])
      knn3_kernel<<<grid(B * M2), 256, 0, stream>>>(xyz2b[cur], (long)M2 * 3, M2,
                                                    xyz3b[cur], M3, ii, iw, B * M2);
      interp_kernel<<<grid(B * O3 * M2), 256, 0, stream>>>(S3bf[cur], ii, iw, l3, O3, 0,
                                                           384, M3, M2, B * O3 * M2);
      copyrows_kernel<<<grid(B * O2 * M2), 256, 0, stream>>>(S2bf[cur], l3, O2, O3, 384,
                                                             M2, B * O2 * M2);
      // l2 = concat([interp(p1<-p2, l3), f1])
      knn3_kernel<<<grid(B * M1), 256, 0, stream>>>(xyz1b[cur], (long)M1 * 3, M1,
                                                    xyz2b[cur], M2, ii, iw, B * M1);
      interp_kernel<<<grid(B * 384 * M1), 256, 0, stream>>>(l3, ii, iw, l2, 384, 0, 448,
                                                            M2, M1, B * 384 * M1);
      copyrows_kernel<<<grid(B * O1 * M1), 256, 0, stream>>>(S1bf[cur], l2, O1, 384, 448,
                                                             M1, B * O1 * M1);
      // l1 = interp(frame<-p1, l2) fused into MLP; frame += motion; emit pred
      knn3_kernel<<<grid(B * N0), 256, 0, stream>>>(frame, (long)N0 * 3, N0, xyz1b[cur],
                                                    M1, ii, iw, B * N0);
      mlp_kernel<<<B * N0, 64, 0, stream>>>(l2, ii, iw, mw1, mb1, mw2, mb2, frame, out, td);
    }
    cur = prev;
  }
  (void)in_sizes; (void)n_in; (void)out_size; (void)ws_size;
}

// Round 5
// 9010.796 us; speedup vs baseline: 1.7812x; 1.7812x over previous
//
#include <hip/hip_runtime.h>

// ---------------- problem constants ----------------
static constexpr int B  = 4;
static constexpr int N0 = 2048;
static constexpr int LF = 8;
static constexpr int M1 = 1024, M2 = 512, M3 = 256;
static constexpr int O1 = 64, O2 = 128, O3 = 256;
static constexpr int NS1 = 12, NS2 = 8, NS3 = 4, NSQ = 4;
static constexpr int C1 = 67, C2 = 195, C3 = 387;

// Exact float32 squared distance in numpy's op order ((dx^2+dy^2)+dz^2),
// with _rn intrinsics to forbid FMA contraction (discrete decisions depend on it).
__device__ __forceinline__ float sq3(float ax, float ay, float az,
                                     float bx, float by, float bz) {
  float dx = __fsub_rn(ax, bx), dy = __fsub_rn(ay, by), dz = __fsub_rn(az, bz);
  return __fadd_rn(__fadd_rn(__fmul_rn(dx, dx), __fmul_rn(dy, dy)),
                   __fmul_rn(dz, dz));
}

// u64-key (hi=dist bits, lo=0x7FFFFFFF-idx) max combine with DPP neighbor fetch.
// VALU pipe only. Self-fallback (old=self) is harmless: max is idempotent.
template <int CTRL>
__device__ __forceinline__ void dpp_max_step(unsigned& hi, unsigned& lo) {
  unsigned ohi = (unsigned)__builtin_amdgcn_update_dpp((int)hi, (int)hi, CTRL, 0xf, 0xf, false);
  unsigned olo = (unsigned)__builtin_amdgcn_update_dpp((int)lo, (int)lo, CTRL, 0xf, 0xf, false);
  bool take = (ohi > hi) || (ohi == hi && olo > lo);
  hi = take ? ohi : hi;
  lo = take ? olo : lo;
}

// ---------------- furthest point sampling (no global ops in the loop) -------
// One block (256 thr = 4 waves) per (batch [, timestep]). Interleaved point
// ownership j = k*256+tid (coalesced staging). dist + own coords in VGPRs
// (launch_bounds(256,1): round-4 profile confirmed residency at VGPR=36).
// Key insight from rounds 1-4: the per-iteration tid0 global store forced a
// vmcnt(0) drain at every __syncthreads (~900 cyc on poisoned workspace).
// Now: selected coords accumulate in LDS sel[]; ONE bulk coalesced global
// write at the end. The loop touches only VALU + LDS.
// Reduce: DPP u64 argmax (round-3 style; round-4's coord-carrying variant was
// 250 cyc/iter slower). Tie-break first-occurrence via lo = 0x7FFFFFFF - j,
// matching jnp.argmax bit-exactly. One parity-double-buffered barrier/iter.
template <int N, int NPOINT>
__global__ __launch_bounds__(256, 1) void fps5(const float* __restrict__ pts,
                                               long s1, long s2,
                                               float* __restrict__ out,
                                               long o1, long o2) {
  constexpr int K = N / 256;
  const float* p = pts + (long)blockIdx.x * s1 + (long)blockIdx.y * s2;
  float* outb = out + (long)blockIdx.x * o1 + (long)blockIdx.y * o2;
  const int tid = threadIdx.x;
  const int lane = tid & 63;
  const int wid = tid >> 6;
  __shared__ float4 sp[N];
  __shared__ float sel[NPOINT * 3];
  __shared__ unsigned long long wbest[2][4];
  float ppx[K], ppy[K], ppz[K], dist[K];
#pragma unroll
  for (int k = 0; k < K; ++k) {
    const int j = k * 256 + tid;
    const float x = p[3 * j + 0], y = p[3 * j + 1], z = p[3 * j + 2];
    ppx[k] = x; ppy[k] = y; ppz[k] = z;
    sp[j] = make_float4(x, y, z, 0.f);
    dist[k] = 1e10f;
  }
  __syncthreads();
  const float4 c0 = sp[0];
  float lx = c0.x, ly = c0.y, lz = c0.z;  // first selected point = index 0
  for (int i = 0; i < NPOINT; ++i) {
    if (tid == 0) {
      sel[3 * i + 0] = lx; sel[3 * i + 1] = ly; sel[3 * i + 2] = lz;
    }
    unsigned bhi = 0u, blo = 0u;
#pragma unroll
    for (int k = 0; k < K; ++k) {
      const float d = sq3(ppx[k], ppy[k], ppz[k], lx, ly, lz);
      const float dm = fminf(dist[k], d);
      dist[k] = dm;
      const unsigned h = __float_as_uint(dm);
      const unsigned l = 0x7FFFFFFFu - (unsigned)(k * 256 + tid);
      const bool take = (h > bhi) || (h == bhi && l > blo);
      bhi = take ? h : bhi;
      blo = take ? l : blo;
    }
    // wave64 max-reduce on VALU pipe; winner lands in lane 63
    dpp_max_step<0x111>(bhi, blo);  // row_shr:1
    dpp_max_step<0x112>(bhi, blo);  // row_shr:2
    dpp_max_step<0x114>(bhi, blo);  // row_shr:4
    dpp_max_step<0x118>(bhi, blo);  // row_shr:8
    dpp_max_step<0x142>(bhi, blo);  // row_bcast15
    dpp_max_step<0x143>(bhi, blo);  // row_bcast31
    if (lane == 63)
      wbest[i & 1][wid] = ((unsigned long long)bhi << 32) | blo;
    __syncthreads();
    unsigned long long gk = 0ull;
#pragma unroll
    for (int w = 0; w < 4; ++w) {
      const unsigned long long e = wbest[i & 1][w];
      gk = (e > gk) ? e : gk;
    }
    const int gidx = 0x7FFFFFFF - (int)(gk & 0xFFFFFFFFu);
    const float4 c = sp[gidx];  // broadcast ds_read_b128
    lx = c.x; ly = c.y; lz = c.z;
  }
  __syncthreads();
  for (int e = tid; e < NPOINT * 3; e += 256) outb[e] = sel[e];
}

// ---------------- ball query ----------------
// First ns in-range indices in ascending order; pad with first; 0 if none.
__global__ __launch_bounds__(256) void bq_kernel(const float* __restrict__ nxyz,
                                                 const float* __restrict__ sxyz,
                                                 float r2, int ns, int M, int Ns,
                                                 int* __restrict__ idx, int total) {
  int t = blockIdx.x * 256 + threadIdx.x;
  if (t >= total) return;
  int b = t / M;
  const float* q = nxyz + (long)t * 3;
  const float qx = q[0], qy = q[1], qz = q[2];
  const float* s = sxyz + (long)b * Ns * 3;
  int* o = idx + (long)t * ns;
  int cnt = 0;
  for (int j = 0; j < Ns; ++j) {
    float d2 = sq3(qx, qy, qz, s[3 * j], s[3 * j + 1], s[3 * j + 2]);
    if (d2 < r2) {
      o[cnt++] = j;
      if (cnt == ns) break;
    }
  }
  int fill = (cnt > 0) ? o[0] : 0;
  for (int k = cnt; k < ns; ++k) o[k] = fill;
}

// ---------------- point-rnn cell: S_out = max_s W @ [S2g; X1; disp] ----------------
// One block per (b,m), blockDim == O. corr transposed [C][NS]; accs[NS] in
// registers so each W element is loaded once.
template <int NS>
__global__ void cell_kernel(const float* __restrict__ P1, const float* __restrict__ X1,
                            const float* __restrict__ P2, const float* __restrict__ S2,
                            const int* __restrict__ idx, const float* __restrict__ W,
                            float* __restrict__ Sout, int M, int Cin, int O) {
  const int C = O + Cin + 3;
  const int bm = blockIdx.x;
  const int b = bm / M, m = bm - b * M;
  extern __shared__ float corrT[];  // [C][NS]
  const int* id = idx + (long)bm * NS;
  const float p1x = P1[bm * 3 + 0], p1y = P1[bm * 3 + 1], p1z = P1[bm * 3 + 2];
  for (int e = threadIdx.x; e < C * NS; e += blockDim.x) {
    const int c = e / NS, s = e - c * NS;
    const int j = id[s];
    float v;
    if (c < O) {
      v = S2[((long)b * O + c) * M + j];
    } else if (c < O + Cin) {
      v = X1[((long)b * Cin + (c - O)) * M + m];
    } else {
      const int d = c - O - Cin;
      const float pj = P2[((long)b * M + j) * 3 + d];
      const float pm = (d == 0) ? p1x : ((d == 1) ? p1y : p1z);
      v = __fsub_rn(pj, pm);
    }
    corrT[e] = v;
  }
  __syncthreads();
  const int o = threadIdx.x;
  const float* w = W + (long)o * C;
  float accs[NS];
#pragma unroll
  for (int s = 0; s < NS; ++s) accs[s] = 0.f;
  for (int c = 0; c < C; ++c) {
    const float wc = w[c];
    const float* cs = corrT + c * NS;
#pragma unroll
    for (int s = 0; s < NS; ++s) accs[s] = fmaf(wc, cs[s], accs[s]);
  }
  float best = accs[0];
#pragma unroll
  for (int s = 1; s < NS; ++s) best = fmaxf(best, accs[s]);
  Sout[((long)b * O + o) * M + m] = best;
}

// ---------------- grouped feature max ----------------
__global__ __launch_bounds__(256) void gmax_kernel(const float* __restrict__ feat,
                                                   const int* __restrict__ idx,
                                                   float* __restrict__ out, int Cc,
                                                   int M, int Ms, int ns, int total) {
  int t = blockIdx.x * 256 + threadIdx.x;
  if (t >= total) return;
  int m = t % M;
  int bc = t / M;
  int b = bc / Cc;
  const int* id = idx + ((long)b * M + m) * ns;
  const float* f = feat + (long)bc * Ms;
  float best = -3.0e38f;
  for (int s = 0; s < ns; ++s) best = fmaxf(best, f[id[s]]);
  out[t] = best;
}

// ---------------- 3-NN + inverse-distance weights ----------------
// Strict '<' insertion matches lax.top_k tie semantics (lower index first).
__global__ __launch_bounds__(256) void knn3_kernel(const float* __restrict__ unk,
                                                   long ubstride, int Mu,
                                                   const float* __restrict__ kn, int Mk,
                                                   int* __restrict__ oi,
                                                   float* __restrict__ ow, int total) {
  int t = blockIdx.x * 256 + threadIdx.x;
  if (t >= total) return;
  int b = t / Mu, m = t - b * Mu;
  const float* q = unk + (long)b * ubstride + (long)m * 3;
  const float qx = q[0], qy = q[1], qz = q[2];
  const float* s = kn + (long)b * Mk * 3;
  float d0 = 3e38f, d1 = 3e38f, d2v = 3e38f;
  int i0 = 0, i1 = 0, i2 = 0;
  for (int j = 0; j < Mk; ++j) {
    float dd = sq3(qx, qy, qz, s[3 * j], s[3 * j + 1], s[3 * j + 2]);
    if (dd < d0) {
      d2v = d1; i2 = i1; d1 = d0; i1 = i0; d0 = dd; i0 = j;
    } else if (dd < d1) {
      d2v = d1; i2 = i1; d1 = dd; i1 = j;
    } else if (dd < d2v) {
      d2v = dd; i2 = j;
    }
  }
  float r0 = 1.0f / __fadd_rn(d0, 1e-8f);
  float r1 = 1.0f / __fadd_rn(d1, 1e-8f);
  float r2 = 1.0f / __fadd_rn(d2v, 1e-8f);
  float sum = __fadd_rn(__fadd_rn(r0, r1), r2);
  ow[t * 3 + 0] = r0 / sum;
  ow[t * 3 + 1] = r1 / sum;
  ow[t * 3 + 2] = r2 / sum;
  oi[t * 3 + 0] = i0;
  oi[t * 3 + 1] = i1;
  oi[t * 3 + 2] = i2;
}

// ---------------- weighted 3-gather (interp) into concat region ----------------
__global__ __launch_bounds__(256) void interp_kernel(const float* __restrict__ f,
                                                     const int* __restrict__ ii,
                                                     const float* __restrict__ iw,
                                                     float* __restrict__ out, int Cc,
                                                     int Coff, int Ctot, int Ms, int Md,
                                                     int total) {
  int t = blockIdx.x * 256 + threadIdx.x;
  if (t >= total) return;
  int m = t % Md;
  int bc = t / Md;
  int c = bc % Cc;
  int b = bc / Cc;
  const int* id = ii + ((long)b * Md + m) * 3;
  const float* w = iw + ((long)b * Md + m) * 3;
  const float* fb = f + ((long)b * Cc + c) * Ms;
  float v = __fadd_rn(__fadd_rn(__fmul_rn(fb[id[0]], w[0]), __fmul_rn(fb[id[1]], w[1])),
                      __fmul_rn(fb[id[2]], w[2]));
  out[((long)b * Ctot + Coff + c) * Md + m] = v;
}

__global__ __launch_bounds__(256) void copyrows_kernel(const float* __restrict__ f,
                                                       float* __restrict__ out, int Cc,
                                                       int Coff, int Ctot, int M,
                                                       int total) {
  int t = blockIdx.x * 256 + threadIdx.x;
  if (t >= total) return;
  int m = t % M;
  int bc = t / M;
  int c = bc % Cc;
  int b = bc / Cc;
  out[((long)b * Ctot + Coff + c) * M + m] = f[t];
}

__global__ __launch_bounds__(256) void copyframe_kernel(const float* __restrict__ xyzs,
                                                        float* __restrict__ frame,
                                                        int total) {
  int t = blockIdx.x * 256 + threadIdx.x;
  if (t >= total) return;
  int b = t / (N0 * 3);
  int rr = t - b * (N0 * 3);
  frame[t] = xyzs[((long)b * LF + (LF / 2 - 1)) * (N0 * 3) + rr];
}

// ---------------- fused interp-to-l1 + 2-layer MLP + frame update ----------------
__global__ __launch_bounds__(64) void mlp_kernel(const float* __restrict__ l2,
                                                 const int* __restrict__ ii,
                                                 const float* __restrict__ iw,
                                                 const float* __restrict__ W1,
                                                 const float* __restrict__ b1,
                                                 const float* __restrict__ W2,
                                                 const float* __restrict__ b2,
                                                 float* __restrict__ frame,
                                                 float* __restrict__ out, int td) {
  const int bn = blockIdx.x;
  const int b = bn / N0, n = bn - b * N0;
  __shared__ float col[448];
  __shared__ float h[64];
  const int* id = ii + (long)bn * 3;
  const float* w = iw + (long)bn * 3;
  const float w0 = w[0], w1 = w[1], w2v = w[2];
  const int i0 = id[0], i1 = id[1], i2 = id[2];
  const float* l2b = l2 + (long)b * 448 * M1;
  for (int c = threadIdx.x; c < 448; c += 64) {
    const float* r = l2b + (long)c * M1;
    col[c] = __fadd_rn(__fadd_rn(__fmul_rn(r[i0], w0), __fmul_rn(r[i1], w1)),
                       __fmul_rn(r[i2], w2v));
  }
  __syncthreads();
  const int o = threadIdx.x;
  const float* wr = W1 + (long)o * 448;
  float acc = b1[o];
  for (int c = 0; c < 448; ++c) acc = fmaf(wr[c], col[c], acc);
  h[o] = fmaxf(acc, 0.0f);
  __syncthreads();
  if (o < 3) {
    const float* w2r = W2 + o * 64;
    float acc2 = b2[o];
    for (int c = 0; c < 64; ++c) acc2 = fmaf(w2r[c], h[c], acc2);
    float nf = frame[(long)bn * 3 + o] + acc2;
    frame[(long)bn * 3 + o] = nf;
    out[(((long)b * 4 + td) * N0 + n) * 3 + o] = nf;
  }
}

extern "C" void kernel_launch(void* const* d_in, const int* in_sizes, int n_in,
                              void* d_out, int out_size, void* d_ws, size_t ws_size,
                              hipStream_t stream) {
  const float* xyzs = (const float*)d_in[0];
  const float* enw[3] = {(const float*)d_in[1], (const float*)d_in[2], (const float*)d_in[3]};
  const float* dew[3] = {(const float*)d_in[4], (const float*)d_in[5], (const float*)d_in[6]};
  const float* mw1 = (const float*)d_in[7];
  const float* mb1 = (const float*)d_in[8];
  const float* mw2 = (const float*)d_in[9];
  const float* mb2 = (const float*)d_in[10];
  float* out = (float*)d_out;

  float* ws = (float*)d_ws;
  size_t off = 0;
  auto alloc = [&](size_t nn) { float* p = ws + off; off += nn; return p; };
  const long st1 = (long)B * M1 * 3, st2 = (long)B * M2 * 3, st3 = (long)B * M3 * 3;
  float* frame = alloc((size_t)B * N0 * 3);
  float* xyz1e = alloc((size_t)4 * st1);  // encoder timesteps 0..3
  float* xyz2e = alloc((size_t)4 * st2);
  float* xyz3e = alloc((size_t)4 * st3);
  float* xyz1d[2] = {alloc((size_t)st1), alloc((size_t)st1)};  // decoder ping-pong
  float* xyz2d[2] = {alloc((size_t)st2), alloc((size_t)st2)};
  float* xyz3d[2] = {alloc((size_t)st3), alloc((size_t)st3)};
  float* z1 = alloc((size_t)st1);  // zero "previous positions" for t=0
  float* z2 = alloc((size_t)st2);
  float* z3 = alloc((size_t)st3);
  float* S1bf[2] = {alloc((size_t)B * O1 * M1), alloc((size_t)B * O1 * M1)};
  float* S2bf[2] = {alloc((size_t)B * O2 * M2), alloc((size_t)B * O2 * M2)};
  float* S3bf[2] = {alloc((size_t)B * O3 * M3), alloc((size_t)B * O3 * M3)};
  float* feat2 = alloc((size_t)B * O1 * M2);
  float* feat3 = alloc((size_t)B * O2 * M3);
  float* l3 = alloc((size_t)B * 384 * M2);
  float* l2 = alloc((size_t)B * 448 * M1);
  float* iw = alloc((size_t)B * N0 * 3);
  int* ii = (int*)alloc((size_t)B * N0 * 3);
  int* idxc = (int*)alloc((size_t)B * M1 * NS1);
  int* idxq = (int*)alloc((size_t)B * M2 * NSQ);

  hipMemsetAsync(z1, 0, (size_t)st1 * 4, stream);
  hipMemsetAsync(z2, 0, (size_t)st2 * 4, stream);
  hipMemsetAsync(z3, 0, (size_t)st3 * 4, stream);
  hipMemsetAsync(S1bf[1], 0, (size_t)B * O1 * M1 * 4, stream);
  hipMemsetAsync(S2bf[1], 0, (size_t)B * O2 * M2 * 4, stream);
  hipMemsetAsync(S3bf[1], 0, (size_t)B * O3 * M3 * 4, stream);

  double r;
  r = 4.0 + 1e-6;             const float r2c1 = (float)(r * r);
  r = 2.0 * 4.0 / 4.0 + 1e-6; const float r2q2 = (float)(r * r);
  r = 2.0 * 4.0 + 1e-6;       const float r2c2 = (float)(r * r);
  r = 4.0 * 4.0 / 4.0 + 1e-6; const float r2q3 = (float)(r * r);
  r = 3.0 * 4.0 + 1e-6;       const float r2c3 = (float)(r * r);

  auto grid = [](int total) { return dim3((unsigned)((total + 255) / 256)); };

  // ---- batched encoder FPS: all 4 encoder timesteps per level in one dispatch
  fps5<2048, 1024><<<dim3(B, 4), 256, 0, stream>>>(xyzs, (long)LF * N0 * 3, (long)N0 * 3,
                                                   xyz1e, (long)M1 * 3, st1);
  fps5<1024, 512><<<dim3(B, 4), 256, 0, stream>>>(xyz1e, (long)M1 * 3, st1,
                                                  xyz2e, (long)M2 * 3, st2);
  fps5<512, 256><<<dim3(B, 4), 256, 0, stream>>>(xyz2e, (long)M2 * 3, st2,
                                                 xyz3e, (long)M3 * 3, st3);

  int cur = 0;
  for (int t = 0; t < LF; ++t) {
    const bool enc = t < LF / 2;
    const float* W1 = enc ? enw[0] : dew[0];
    const float* W2 = enc ? enw[1] : dew[1];
    const float* W3 = enc ? enw[2] : dew[2];
    const int prev = 1 - cur;
    if (!enc && t == LF / 2)
      copyframe_kernel<<<grid(B * N0 * 3), 256, 0, stream>>>(xyzs, frame, B * N0 * 3);

    const float *x1c, *x1p, *x2c, *x2p, *x3c, *x3p;
    if (enc) {
      x1c = xyz1e + (long)t * st1; x1p = t ? xyz1e + (long)(t - 1) * st1 : z1;
      x2c = xyz2e + (long)t * st2; x2p = t ? xyz2e + (long)(t - 1) * st2 : z2;
      x3c = xyz3e + (long)t * st3; x3p = t ? xyz3e + (long)(t - 1) * st3 : z3;
    } else {
      x1c = xyz1d[cur]; x1p = (t == LF / 2) ? xyz1e + 3 * st1 : xyz1d[prev];
      x2c = xyz2d[cur]; x2p = (t == LF / 2) ? xyz2e + 3 * st2 : xyz2d[prev];
      x3c = xyz3d[cur]; x3p = (t == LF / 2) ? xyz3e + 3 * st3 : xyz3d[prev];
    }

    // ---- level 1 ----
    if (!enc)
      fps5<2048, 1024><<<dim3(B, 1), 256, 0, stream>>>(frame, (long)N0 * 3, 0,
                                                       (float*)x1c, (long)M1 * 3, 0);
    bq_kernel<<<grid(B * M1), 256, 0, stream>>>(x1c, x1p, r2c1, NS1, M1, M1, idxc, B * M1);
    cell_kernel<NS1><<<B * M1, O1, C1 * NS1 * 4, stream>>>(x1c, nullptr, x1p, S1bf[prev],
                                                           idxc, W1, S1bf[cur], M1, 0, O1);
    // ---- level 2 ----
    if (!enc)
      fps5<1024, 512><<<dim3(B, 1), 256, 0, stream>>>(x1c, (long)M1 * 3, 0,
                                                      (float*)x2c, (long)M2 * 3, 0);
    bq_kernel<<<grid(B * M2), 256, 0, stream>>>(x2c, x1c, r2q2, NSQ, M2, M1, idxq, B * M2);
    gmax_kernel<<<grid(B * O1 * M2), 256, 0, stream>>>(S1bf[cur], idxq, feat2, O1, M2, M1,
                                                       NSQ, B * O1 * M2);
    bq_kernel<<<grid(B * M2), 256, 0, stream>>>(x2c, x2p, r2c2, NS2, M2, M2, idxc, B * M2);
    cell_kernel<NS2><<<B * M2, O2, C2 * NS2 * 4, stream>>>(x2c, feat2, x2p, S2bf[prev],
                                                           idxc, W2, S2bf[cur], M2, O1, O2);
    // ---- level 3 ----
    if (!enc)
      fps5<512, 256><<<dim3(B, 1), 256, 0, stream>>>(x2c, (long)M2 * 3, 0,
                                                     (float*)x3c, (long)M3 * 3, 0);
    bq_kernel<<<grid(B * M3), 256, 0, stream>>>(x3c, x2c, r2q3, NSQ, M3, M2, idxq, B * M3);
    gmax_kernel<<<grid(B * O2 * M3), 256, 0, stream>>>(S2bf[cur], idxq, feat3, O2, M3, M2,
                                                       NSQ, B * O2 * M3);
    bq_kernel<<<grid(B * M3), 256, 0, stream>>>(x3c, x3p, r2c3, NS3, M3, M3, idxc, B * M3);
    cell_kernel<NS3><<<B * M3, O3, C3 * NS3 * 4, stream>>>(x3c, feat3, x3p, S3bf[prev],
                                                           idxc, W3, S3bf[cur], M3, O2, O3);

    if (!enc) {
      const int td = t - LF / 2;
      // l3 = concat([interp(p2<-p3, f3), f2])
      knn3_kernel<<<grid(B * M2), 256, 0, stream>>>(x2c, (long)M2 * 3, M2, x3c, M3, ii, iw,
                                                    B * M2);
      interp_kernel<<<grid(B * O3 * M2), 256, 0, stream>>>(S3bf[cur], ii, iw, l3, O3, 0,
                                                           384, M3, M2, B * O3 * M2);
      copyrows_kernel<<<grid(B * O2 * M2), 256, 0, stream>>>(S2bf[cur], l3, O2, O3, 384,
                                                             M2, B * O2 * M2);
      // l2 = concat([interp(p1<-p2, l3), f1])
      knn3_kernel<<<grid(B * M1), 256, 0, stream>>>(x1c, (long)M1 * 3, M1, x2c, M2, ii, iw,
                                                    B * M1);
      interp_kernel<<<grid(B * 384 * M1), 256, 0, stream>>>(l3, ii, iw, l2, 384, 0, 448,
                                                            M2, M1, B * 384 * M1);
      copyrows_kernel<<<grid(B * O1 * M1), 256, 0, stream>>>(S1bf[cur], l2, O1, 384, 448,
                                                             M1, B * O1 * M1);
      // l1 = interp(frame<-p1, l2) fused into MLP; frame += motion; emit pred
      knn3_kernel<<<grid(B * N0), 256, 0, stream>>>(frame, (long)N0 * 3, N0, x1c, M1, ii,
                                                    iw, B * N0);
      mlp_kernel<<<B * N0, 64, 0, stream>>>(l2, ii, iw, mw1, mb1, mw2, mb2, frame, out, td);
    }
    cur = prev;
  }
  (void)in_sizes; (void)n_in; (void)out_size; (void)ws_size;
}

// Round 6
// 7344.469 us; speedup vs baseline: 2.1854x; 1.2269x over previous
//
#include <hip/hip_runtime.h>

// ---------------- problem constants ----------------
static constexpr int B  = 4;
static constexpr int N0 = 2048;
static constexpr int LF = 8;
static constexpr int M1 = 1024, M2 = 512, M3 = 256;
static constexpr int O1 = 64, O2 = 128, O3 = 256;
static constexpr int NS1 = 12, NS2 = 8, NS3 = 4, NSQ = 4;
static constexpr int C1 = 67, C2 = 195, C3 = 387;
// Uniform per-batch stride (floats) for all sampled-xyz arrays. Levels 2/3 are
// PREFIXES of the level-1 FPS output (FPS hierarchical-consistency: re-running
// FPS on the selection-ordered gather reproduces the truncated order bit-exactly
// — same coords, same ops, same first-occurrence tie-break), so all levels view
// the same buffer with this stride.
static constexpr long XS = 3 * (long)M1;

// Exact float32 squared distance in numpy's op order ((dx^2+dy^2)+dz^2),
// with _rn intrinsics to forbid FMA contraction (discrete decisions depend on it).
__device__ __forceinline__ float sq3(float ax, float ay, float az,
                                     float bx, float by, float bz) {
  float dx = __fsub_rn(ax, bx), dy = __fsub_rn(ay, by), dz = __fsub_rn(az, bz);
  return __fadd_rn(__fadd_rn(__fmul_rn(dx, dx), __fmul_rn(dy, dy)),
                   __fmul_rn(dz, dz));
}

// u64-key (hi=dist bits, lo=0x7FFFFFFF-idx) max combine with DPP neighbor fetch.
// VALU pipe only. Self-fallback (old=self) is harmless: max is idempotent.
template <int CTRL>
__device__ __forceinline__ void dpp_max_step(unsigned& hi, unsigned& lo) {
  unsigned ohi = (unsigned)__builtin_amdgcn_update_dpp((int)hi, (int)hi, CTRL, 0xf, 0xf, false);
  unsigned olo = (unsigned)__builtin_amdgcn_update_dpp((int)lo, (int)lo, CTRL, 0xf, 0xf, false);
  bool take = (ohi > hi) || (ohi == hi && olo > lo);
  hi = take ? ohi : hi;
  lo = take ? olo : lo;
}

// ---------------- furthest point sampling (no global ops in the loop) -------
// One block (256 thr = 4 waves) per (batch [, timestep]). Interleaved point
// ownership j = k*256+tid. dist + own coords in VGPRs. Loop touches only
// VALU + LDS (round-5: removing the per-iter global store was the big win).
// DPP u64 argmax; tie-break first-occurrence via lo = 0x7FFFFFFF - j, matching
// jnp.argmax bit-exactly. One parity-double-buffered barrier per iteration.
template <int N, int NPOINT>
__global__ __launch_bounds__(256, 1) void fps5(const float* __restrict__ pts,
                                               long s1, long s2,
                                               float* __restrict__ out,
                                               long o1, long o2) {
  constexpr int K = N / 256;
  const float* p = pts + (long)blockIdx.x * s1 + (long)blockIdx.y * s2;
  float* outb = out + (long)blockIdx.x * o1 + (long)blockIdx.y * o2;
  const int tid = threadIdx.x;
  const int lane = tid & 63;
  const int wid = tid >> 6;
  __shared__ float4 sp[N];
  __shared__ float sel[NPOINT * 3];
  __shared__ unsigned long long wbest[2][4];
  float ppx[K], ppy[K], ppz[K], dist[K];
#pragma unroll
  for (int k = 0; k < K; ++k) {
    const int j = k * 256 + tid;
    const float x = p[3 * j + 0], y = p[3 * j + 1], z = p[3 * j + 2];
    ppx[k] = x; ppy[k] = y; ppz[k] = z;
    sp[j] = make_float4(x, y, z, 0.f);
    dist[k] = 1e10f;
  }
  __syncthreads();
  const float4 c0 = sp[0];
  float lx = c0.x, ly = c0.y, lz = c0.z;  // first selected point = index 0
  for (int i = 0; i < NPOINT; ++i) {
    if (tid == 0) {
      sel[3 * i + 0] = lx; sel[3 * i + 1] = ly; sel[3 * i + 2] = lz;
    }
    unsigned bhi = 0u, blo = 0u;
#pragma unroll
    for (int k = 0; k < K; ++k) {
      const float d = sq3(ppx[k], ppy[k], ppz[k], lx, ly, lz);
      const float dm = fminf(dist[k], d);
      dist[k] = dm;
      const unsigned h = __float_as_uint(dm);
      const unsigned l = 0x7FFFFFFFu - (unsigned)(k * 256 + tid);
      const bool take = (h > bhi) || (h == bhi && l > blo);
      bhi = take ? h : bhi;
      blo = take ? l : blo;
    }
    // wave64 max-reduce on VALU pipe; winner lands in lane 63
    dpp_max_step<0x111>(bhi, blo);  // row_shr:1
    dpp_max_step<0x112>(bhi, blo);  // row_shr:2
    dpp_max_step<0x114>(bhi, blo);  // row_shr:4
    dpp_max_step<0x118>(bhi, blo);  // row_shr:8
    dpp_max_step<0x142>(bhi, blo);  // row_bcast15
    dpp_max_step<0x143>(bhi, blo);  // row_bcast31
    if (lane == 63)
      wbest[i & 1][wid] = ((unsigned long long)bhi << 32) | blo;
    __syncthreads();
    unsigned long long gk = 0ull;
#pragma unroll
    for (int w = 0; w < 4; ++w) {
      const unsigned long long e = wbest[i & 1][w];
      gk = (e > gk) ? e : gk;
    }
    const int gidx = 0x7FFFFFFF - (int)(gk & 0xFFFFFFFFu);
    const float4 c = sp[gidx];  // broadcast ds_read_b128
    lx = c.x; ly = c.y; lz = c.z;
  }
  __syncthreads();
  for (int e = tid; e < NPOINT * 3; e += 256) outb[e] = sel[e];
}

// ---------------- ball query ----------------
// First ns in-range indices in ascending order; pad with first; 0 if none.
// nstr/sstr: per-batch float strides (xyz arrays may be prefixes of a larger
// stride-XS buffer).
__global__ __launch_bounds__(256) void bq_kernel(const float* __restrict__ nxyz, long nstr,
                                                 const float* __restrict__ sxyz, long sstr,
                                                 float r2, int ns, int M, int Ns,
                                                 int* __restrict__ idx, int total) {
  int t = blockIdx.x * 256 + threadIdx.x;
  if (t >= total) return;
  int b = t / M, m = t - b * M;
  const float* q = nxyz + (long)b * nstr + (long)m * 3;
  const float qx = q[0], qy = q[1], qz = q[2];
  const float* s = sxyz + (long)b * sstr;
  int* o = idx + (long)t * ns;
  int cnt = 0;
  for (int j = 0; j < Ns; ++j) {
    float d2 = sq3(qx, qy, qz, s[3 * j], s[3 * j + 1], s[3 * j + 2]);
    if (d2 < r2) {
      o[cnt++] = j;
      if (cnt == ns) break;
    }
  }
  int fill = (cnt > 0) ? o[0] : 0;
  for (int k = cnt; k < ns; ++k) o[k] = fill;
}

// ---------------- point-rnn cell: S_out = max_s W @ [S2g; X1; disp] ----------------
// One block per (b,m), blockDim == O. corr transposed [C][NS]; accs[NS] in
// registers so each W element is loaded once. p1s/p2s: xyz batch strides.
template <int NS>
__global__ void cell_kernel(const float* __restrict__ P1, long p1s,
                            const float* __restrict__ X1,
                            const float* __restrict__ P2, long p2s,
                            const float* __restrict__ S2,
                            const int* __restrict__ idx, const float* __restrict__ W,
                            float* __restrict__ Sout, int M, int Cin, int O) {
  const int C = O + Cin + 3;
  const int bm = blockIdx.x;
  const int b = bm / M, m = bm - b * M;
  extern __shared__ float corrT[];  // [C][NS]
  const int* id = idx + (long)bm * NS;
  const float* p1 = P1 + (long)b * p1s + (long)m * 3;
  const float p1x = p1[0], p1y = p1[1], p1z = p1[2];
  for (int e = threadIdx.x; e < C * NS; e += blockDim.x) {
    const int c = e / NS, s = e - c * NS;
    const int j = id[s];
    float v;
    if (c < O) {
      v = S2[((long)b * O + c) * M + j];
    } else if (c < O + Cin) {
      v = X1[((long)b * Cin + (c - O)) * M + m];
    } else {
      const int d = c - O - Cin;
      const float pj = P2[(long)b * p2s + (long)j * 3 + d];
      const float pm = (d == 0) ? p1x : ((d == 1) ? p1y : p1z);
      v = __fsub_rn(pj, pm);
    }
    corrT[e] = v;
  }
  __syncthreads();
  const int o = threadIdx.x;
  const float* w = W + (long)o * C;
  float accs[NS];
#pragma unroll
  for (int s = 0; s < NS; ++s) accs[s] = 0.f;
  for (int c = 0; c < C; ++c) {
    const float wc = w[c];
    const float* cs = corrT + c * NS;
#pragma unroll
    for (int s = 0; s < NS; ++s) accs[s] = fmaf(wc, cs[s], accs[s]);
  }
  float best = accs[0];
#pragma unroll
  for (int s = 1; s < NS; ++s) best = fmaxf(best, accs[s]);
  Sout[((long)b * O + o) * M + m] = best;
}

// ---------------- grouped feature max ----------------
__global__ __launch_bounds__(256) void gmax_kernel(const float* __restrict__ feat,
                                                   const int* __restrict__ idx,
                                                   float* __restrict__ out, int Cc,
                                                   int M, int Ms, int ns, int total) {
  int t = blockIdx.x * 256 + threadIdx.x;
  if (t >= total) return;
  int m = t % M;
  int bc = t / M;
  int b = bc / Cc;
  const int* id = idx + ((long)b * M + m) * ns;
  const float* f = feat + (long)bc * Ms;
  float best = -3.0e38f;
  for (int s = 0; s < ns; ++s) best = fmaxf(best, f[id[s]]);
  out[t] = best;
}

// ---------------- 3-NN + inverse-distance weights ----------------
// Strict '<' insertion matches lax.top_k tie semantics (lower index first).
__global__ __launch_bounds__(256) void knn3_kernel(const float* __restrict__ unk,
                                                   long ustr, int Mu,
                                                   const float* __restrict__ kn,
                                                   long kstr, int Mk,
                                                   int* __restrict__ oi,
                                                   float* __restrict__ ow, int total) {
  int t = blockIdx.x * 256 + threadIdx.x;
  if (t >= total) return;
  int b = t / Mu, m = t - b * Mu;
  const float* q = unk + (long)b * ustr + (long)m * 3;
  const float qx = q[0], qy = q[1], qz = q[2];
  const float* s = kn + (long)b * kstr;
  float d0 = 3e38f, d1 = 3e38f, d2v = 3e38f;
  int i0 = 0, i1 = 0, i2 = 0;
  for (int j = 0; j < Mk; ++j) {
    float dd = sq3(qx, qy, qz, s[3 * j], s[3 * j + 1], s[3 * j + 2]);
    if (dd < d0) {
      d2v = d1; i2 = i1; d1 = d0; i1 = i0; d0 = dd; i0 = j;
    } else if (dd < d1) {
      d2v = d1; i2 = i1; d1 = dd; i1 = j;
    } else if (dd < d2v) {
      d2v = dd; i2 = j;
    }
  }
  float r0 = 1.0f / __fadd_rn(d0, 1e-8f);
  float r1 = 1.0f / __fadd_rn(d1, 1e-8f);
  float r2 = 1.0f / __fadd_rn(d2v, 1e-8f);
  float sum = __fadd_rn(__fadd_rn(r0, r1), r2);
  ow[t * 3 + 0] = r0 / sum;
  ow[t * 3 + 1] = r1 / sum;
  ow[t * 3 + 2] = r2 / sum;
  oi[t * 3 + 0] = i0;
  oi[t * 3 + 1] = i1;
  oi[t * 3 + 2] = i2;
}

// ---------------- weighted 3-gather (interp) into concat region ----------------
__global__ __launch_bounds__(256) void interp_kernel(const float* __restrict__ f,
                                                     const int* __restrict__ ii,
                                                     const float* __restrict__ iw,
                                                     float* __restrict__ out, int Cc,
                                                     int Coff, int Ctot, int Ms, int Md,
                                                     int total) {
  int t = blockIdx.x * 256 + threadIdx.x;
  if (t >= total) return;
  int m = t % Md;
  int bc = t / Md;
  int c = bc % Cc;
  int b = bc / Cc;
  const int* id = ii + ((long)b * Md + m) * 3;
  const float* w = iw + ((long)b * Md + m) * 3;
  const float* fb = f + ((long)b * Cc + c) * Ms;
  float v = __fadd_rn(__fadd_rn(__fmul_rn(fb[id[0]], w[0]), __fmul_rn(fb[id[1]], w[1])),
                      __fmul_rn(fb[id[2]], w[2]));
  out[((long)b * Ctot + Coff + c) * Md + m] = v;
}

__global__ __launch_bounds__(256) void copyrows_kernel(const float* __restrict__ f,
                                                       float* __restrict__ out, int Cc,
                                                       int Coff, int Ctot, int M,
                                                       int total) {
  int t = blockIdx.x * 256 + threadIdx.x;
  if (t >= total) return;
  int m = t % M;
  int bc = t / M;
  int c = bc % Cc;
  int b = bc / Cc;
  out[((long)b * Ctot + Coff + c) * M + m] = f[t];
}

__global__ __launch_bounds__(256) void copyframe_kernel(const float* __restrict__ xyzs,
                                                        float* __restrict__ frame,
                                                        int total) {
  int t = blockIdx.x * 256 + threadIdx.x;
  if (t >= total) return;
  int b = t / (N0 * 3);
  int rr = t - b * (N0 * 3);
  frame[t] = xyzs[((long)b * LF + (LF / 2 - 1)) * (N0 * 3) + rr];
}

// ---------------- fused interp-to-l1 + 2-layer MLP + frame update ----------------
__global__ __launch_bounds__(64) void mlp_kernel(const float* __restrict__ l2,
                                                 const int* __restrict__ ii,
                                                 const float* __restrict__ iw,
                                                 const float* __restrict__ W1,
                                                 const float* __restrict__ b1,
                                                 const float* __restrict__ W2,
                                                 const float* __restrict__ b2,
                                                 float* __restrict__ frame,
                                                 float* __restrict__ out, int td) {
  const int bn = blockIdx.x;
  const int b = bn / N0, n = bn - b * N0;
  __shared__ float col[448];
  __shared__ float h[64];
  const int* id = ii + (long)bn * 3;
  const float* w = iw + (long)bn * 3;
  const float w0 = w[0], w1 = w[1], w2v = w[2];
  const int i0 = id[0], i1 = id[1], i2 = id[2];
  const float* l2b = l2 + (long)b * 448 * M1;
  for (int c = threadIdx.x; c < 448; c += 64) {
    const float* r = l2b + (long)c * M1;
    col[c] = __fadd_rn(__fadd_rn(__fmul_rn(r[i0], w0), __fmul_rn(r[i1], w1)),
                       __fmul_rn(r[i2], w2v));
  }
  __syncthreads();
  const int o = threadIdx.x;
  const float* wr = W1 + (long)o * 448;
  float acc = b1[o];
  for (int c = 0; c < 448; ++c) acc = fmaf(wr[c], col[c], acc);
  h[o] = fmaxf(acc, 0.0f);
  __syncthreads();
  if (o < 3) {
    const float* w2r = W2 + o * 64;
    float acc2 = b2[o];
    for (int c = 0; c < 64; ++c) acc2 = fmaf(w2r[c], h[c], acc2);
    float nf = frame[(long)bn * 3 + o] + acc2;
    frame[(long)bn * 3 + o] = nf;
    out[(((long)b * 4 + td) * N0 + n) * 3 + o] = nf;
  }
}

extern "C" void kernel_launch(void* const* d_in, const int* in_sizes, int n_in,
                              void* d_out, int out_size, void* d_ws, size_t ws_size,
                              hipStream_t stream) {
  const float* xyzs = (const float*)d_in[0];
  const float* enw[3] = {(const float*)d_in[1], (const float*)d_in[2], (const float*)d_in[3]};
  const float* dew[3] = {(const float*)d_in[4], (const float*)d_in[5], (const float*)d_in[6]};
  const float* mw1 = (const float*)d_in[7];
  const float* mb1 = (const float*)d_in[8];
  const float* mw2 = (const float*)d_in[9];
  const float* mb2 = (const float*)d_in[10];
  float* out = (float*)d_out;

  float* ws = (float*)d_ws;
  size_t off = 0;
  auto alloc = [&](size_t nn) { float* p = ws + off; off += nn; return p; };
  const long st1 = (long)B * M1 * 3;
  float* frame = alloc((size_t)B * N0 * 3);
  float* xyz1e = alloc((size_t)4 * st1);  // encoder timesteps 0..3 (levels 2/3 = prefixes)
  float* xyz1d[2] = {alloc((size_t)st1), alloc((size_t)st1)};  // decoder ping-pong
  float* z1 = alloc((size_t)st1);  // zero "previous positions" (all levels, stride XS)
  float* S1bf[2] = {alloc((size_t)B * O1 * M1), alloc((size_t)B * O1 * M1)};
  float* S2bf[2] = {alloc((size_t)B * O2 * M2), alloc((size_t)B * O2 * M2)};
  float* S3bf[2] = {alloc((size_t)B * O3 * M3), alloc((size_t)B * O3 * M3)};
  float* feat2 = alloc((size_t)B * O1 * M2);
  float* feat3 = alloc((size_t)B * O2 * M3);
  float* l3 = alloc((size_t)B * 384 * M2);
  float* l2 = alloc((size_t)B * 448 * M1);
  float* iw = alloc((size_t)B * N0 * 3);
  int* ii = (int*)alloc((size_t)B * N0 * 3);
  int* idxc = (int*)alloc((size_t)B * M1 * NS1);
  int* idxq = (int*)alloc((size_t)B * M2 * NSQ);

  hipMemsetAsync(z1, 0, (size_t)st1 * 4, stream);
  hipMemsetAsync(S1bf[1], 0, (size_t)B * O1 * M1 * 4, stream);
  hipMemsetAsync(S2bf[1], 0, (size_t)B * O2 * M2 * 4, stream);
  hipMemsetAsync(S3bf[1], 0, (size_t)B * O3 * M3 * 4, stream);

  double r;
  r = 4.0 + 1e-6;             const float r2c1 = (float)(r * r);
  r = 2.0 * 4.0 / 4.0 + 1e-6; const float r2q2 = (float)(r * r);
  r = 2.0 * 4.0 + 1e-6;       const float r2c2 = (float)(r * r);
  r = 4.0 * 4.0 / 4.0 + 1e-6; const float r2q3 = (float)(r * r);
  r = 3.0 * 4.0 + 1e-6;       const float r2c3 = (float)(r * r);

  auto grid = [](int total) { return dim3((unsigned)((total + 255) / 256)); };

  // ---- batched encoder FPS: all 4 encoder timesteps, level 1 only (levels 2/3
  // are prefixes of the level-1 output by FPS hierarchical consistency)
  fps5<2048, 1024><<<dim3(B, 4), 256, 0, stream>>>(xyzs, (long)LF * N0 * 3, (long)N0 * 3,
                                                   xyz1e, XS, st1);

  int cur = 0;
  for (int t = 0; t < LF; ++t) {
    const bool enc = t < LF / 2;
    const float* W1 = enc ? enw[0] : dew[0];
    const float* W2 = enc ? enw[1] : dew[1];
    const float* W3 = enc ? enw[2] : dew[2];
    const int prev = 1 - cur;
    if (!enc && t == LF / 2)
      copyframe_kernel<<<grid(B * N0 * 3), 256, 0, stream>>>(xyzs, frame, B * N0 * 3);

    // one xyz buffer per timestep; levels 2/3 alias its per-batch prefix (stride XS)
    const float *x1c, *x1p;
    if (enc) {
      x1c = xyz1e + (long)t * st1;
      x1p = t ? xyz1e + (long)(t - 1) * st1 : z1;
    } else {
      x1c = xyz1d[cur];
      x1p = (t == LF / 2) ? xyz1e + 3 * st1 : xyz1d[prev];
    }

    // ---- level 1 ----
    if (!enc)
      fps5<2048, 1024><<<dim3(B, 1), 256, 0, stream>>>(frame, (long)N0 * 3, 0,
                                                       (float*)x1c, XS, 0);
    bq_kernel<<<grid(B * M1), 256, 0, stream>>>(x1c, XS, x1p, XS, r2c1, NS1, M1, M1,
                                                idxc, B * M1);
    cell_kernel<NS1><<<B * M1, O1, C1 * NS1 * 4, stream>>>(x1c, XS, nullptr, x1p, XS,
                                                           S1bf[prev], idxc, W1, S1bf[cur],
                                                           M1, 0, O1);
    // ---- level 2 (xyz = prefix of level 1) ----
    bq_kernel<<<grid(B * M2), 256, 0, stream>>>(x1c, XS, x1c, XS, r2q2, NSQ, M2, M1,
                                                idxq, B * M2);
    gmax_kernel<<<grid(B * O1 * M2), 256, 0, stream>>>(S1bf[cur], idxq, feat2, O1, M2, M1,
                                                       NSQ, B * O1 * M2);
    bq_kernel<<<grid(B * M2), 256, 0, stream>>>(x1c, XS, x1p, XS, r2c2, NS2, M2, M2,
                                                idxc, B * M2);
    cell_kernel<NS2><<<B * M2, O2, C2 * NS2 * 4, stream>>>(x1c, XS, feat2, x1p, XS,
                                                           S2bf[prev], idxc, W2, S2bf[cur],
                                                           M2, O1, O2);
    // ---- level 3 (xyz = prefix of level 1) ----
    bq_kernel<<<grid(B * M3), 256, 0, stream>>>(x1c, XS, x1c, XS, r2q3, NSQ, M3, M2,
                                                idxq, B * M3);
    gmax_kernel<<<grid(B * O2 * M3), 256, 0, stream>>>(S2bf[cur], idxq, feat3, O2, M3, M2,
                                                       NSQ, B * O2 * M3);
    bq_kernel<<<grid(B * M3), 256, 0, stream>>>(x1c, XS, x1p, XS, r2c3, NS3, M3, M3,
                                                idxc, B * M3);
    cell_kernel<NS3><<<B * M3, O3, C3 * NS3 * 4, stream>>>(x1c, XS, feat3, x1p, XS,
                                                           S3bf[prev], idxc, W3, S3bf[cur],
                                                           M3, O2, O3);

    if (!enc) {
      const int td = t - LF / 2;
      // l3 = concat([interp(p2<-p3, f3), f2])
      knn3_kernel<<<grid(B * M2), 256, 0, stream>>>(x1c, XS, M2, x1c, XS, M3, ii, iw,
                                                    B * M2);
      interp_kernel<<<grid(B * O3 * M2), 256, 0, stream>>>(S3bf[cur], ii, iw, l3, O3, 0,
                                                           384, M3, M2, B * O3 * M2);
      copyrows_kernel<<<grid(B * O2 * M2), 256, 0, stream>>>(S2bf[cur], l3, O2, O3, 384,
                                                             M2, B * O2 * M2);
      // l2 = concat([interp(p1<-p2, l3), f1])
      knn3_kernel<<<grid(B * M1), 256, 0, stream>>>(x1c, XS, M1, x1c, XS, M2, ii, iw,
                                                    B * M1);
      interp_kernel<<<grid(B * 384 * M1), 256, 0, stream>>>(l3, ii, iw, l2, 384, 0, 448,
                                                            M2, M1, B * 384 * M1);
      copyrows_kernel<<<grid(B * O1 * M1), 256, 0, stream>>>(S1bf[cur], l2, O1, 384, 448,
                                                             M1, B * O1 * M1);
      // l1 = interp(frame<-p1, l2) fused into MLP; frame += motion; emit pred
      knn3_kernel<<<grid(B * N0), 256, 0, stream>>>(frame, (long)N0 * 3, N0, x1c, XS, M1,
                                                    ii, iw, B * N0);
      mlp_kernel<<<B * N0, 64, 0, stream>>>(l2, ii, iw, mw1, mb1, mw2, mb2, frame, out, td);
    }
    cur = prev;
  }
  (void)in_sizes; (void)n_in; (void)out_size; (void)ws_size;
}

// Round 7
// 5726.420 us; speedup vs baseline: 2.8029x; 1.2826x over previous
//
#include <hip/hip_runtime.h>

// ---------------- problem constants ----------------
static constexpr int B  = 4;
static constexpr int N0 = 2048;
static constexpr int LF = 8;
static constexpr int M1 = 1024, M2 = 512, M3 = 256;
static constexpr int O1 = 64, O2 = 128, O3 = 256;
static constexpr int NS1 = 12, NS2 = 8, NS3 = 4, NSQ = 4;
static constexpr int C1 = 67, C2 = 195, C3 = 387;
// Per-batch stride (floats) for all sampled-xyz arrays. Levels 2/3 are PREFIXES
// of the level-1 FPS output (FPS hierarchical consistency, verified bit-exact
// rounds 6); all levels view the same buffer with this stride.
static constexpr long XS = 3 * (long)M1;

// Exact float32 squared distance in numpy's op order ((dx^2+dy^2)+dz^2),
// with _rn intrinsics to forbid FMA contraction (discrete decisions depend on it).
__device__ __forceinline__ float sq3(float ax, float ay, float az,
                                     float bx, float by, float bz) {
  float dx = __fsub_rn(ax, bx), dy = __fsub_rn(ay, by), dz = __fsub_rn(az, bz);
  return __fadd_rn(__fadd_rn(__fmul_rn(dx, dx), __fmul_rn(dy, dy)),
                   __fmul_rn(dz, dz));
}

// u64-key (hi=dist bits, lo=0x7FFFFFFF-idx) max combine with DPP neighbor fetch.
// VALU pipe only. Self-fallback (old=self) harmless: max is idempotent.
template <int CTRL>
__device__ __forceinline__ void dpp_max_step(unsigned& hi, unsigned& lo) {
  unsigned ohi = (unsigned)__builtin_amdgcn_update_dpp((int)hi, (int)hi, CTRL, 0xf, 0xf, false);
  unsigned olo = (unsigned)__builtin_amdgcn_update_dpp((int)lo, (int)lo, CTRL, 0xf, 0xf, false);
  bool take = (ohi > hi) || (ohi == hi && olo > lo);
  hi = take ? ohi : hi;
  lo = take ? olo : lo;
}

// ---------------- furthest point sampling v6 ----------------
// One block (256 thr = 4 waves) per (batch [, timestep]). All state in VGPRs.
// Per iteration: k-loop tracks local-best key AND coords (cndmask, throughput);
// DPP reduces only the u64 key (round-4: coord-carry through DPP regressed);
// the unique owner lane (local key == wave key; keys are index-unique) publishes
// key+coords to LDS; ONE parity-double-buffered barrier; batched read of 4 keys
// + 4 float4s; cndmask combine -> selected coords with no second dependent LDS
// read. Selections accumulate in owner-thread registers; one bulk global write
// at the end (round 5: no global ops in the loop). Tie-break = first occurrence
// via lo = 0x7FFFFFFF - j, matching jnp.argmax bit-exactly.
template <int N, int NPOINT>
__global__ __launch_bounds__(256, 1) void fps6(const float* __restrict__ pts,
                                               long s1, long s2,
                                               float* __restrict__ out,
                                               long o1, long o2) {
  constexpr int K = N / 256;
  constexpr int KS = NPOINT / 256;
  const float* p = pts + (long)blockIdx.x * s1 + (long)blockIdx.y * s2;
  float* outb = out + (long)blockIdx.x * o1 + (long)blockIdx.y * o2;
  const int tid = threadIdx.x;
  const int wid = tid >> 6;
  __shared__ unsigned long long skey[2][4];
  __shared__ float4 scrd[2][4];
  float ppx[K], ppy[K], ppz[K], dist[K];
  float sx[KS], sy[KS], sz[KS];
#pragma unroll
  for (int k = 0; k < K; ++k) {
    const int j = k * 256 + tid;
    ppx[k] = p[3 * j + 0];
    ppy[k] = p[3 * j + 1];
    ppz[k] = p[3 * j + 2];
    dist[k] = 1e10f;
  }
  float lx = p[0], ly = p[1], lz = p[2];  // first selected point = index 0
#pragma unroll
  for (int q = 0; q < KS; ++q) {
    for (int r = 0; r < 256; ++r) {
      if (r == tid) { sx[q] = lx; sy[q] = ly; sz[q] = lz; }
      unsigned bhi = 0u, blo = 0u;
      float bx = lx, by = ly, bz = lz;
#pragma unroll
      for (int k = 0; k < K; ++k) {
        const float d = sq3(ppx[k], ppy[k], ppz[k], lx, ly, lz);
        const float dm = fminf(dist[k], d);
        dist[k] = dm;
        const unsigned h = __float_as_uint(dm);
        const unsigned l = 0x7FFFFFFFu - (unsigned)(k * 256 + tid);
        const bool take = (h > bhi) || (h == bhi && l > blo);
        bhi = take ? h : bhi;
        blo = take ? l : blo;
        bx = take ? ppx[k] : bx;
        by = take ? ppy[k] : by;
        bz = take ? ppz[k] : bz;
      }
      // wave64 key reduce on VALU pipe; winner key lands in lane 63
      unsigned rhi = bhi, rlo = blo;
      dpp_max_step<0x111>(rhi, rlo);  // row_shr:1
      dpp_max_step<0x112>(rhi, rlo);  // row_shr:2
      dpp_max_step<0x114>(rhi, rlo);  // row_shr:4
      dpp_max_step<0x118>(rhi, rlo);  // row_shr:8
      dpp_max_step<0x142>(rhi, rlo);  // row_bcast15
      dpp_max_step<0x143>(rhi, rlo);  // row_bcast31
      const unsigned whi = (unsigned)__builtin_amdgcn_readlane((int)rhi, 63);
      const unsigned wlo = (unsigned)__builtin_amdgcn_readlane((int)rlo, 63);
      if (bhi == whi && blo == wlo) {  // exactly one lane per wave (keys unique)
        skey[r & 1][wid] = ((unsigned long long)whi << 32) | wlo;
        scrd[r & 1][wid] = make_float4(bx, by, bz, 0.f);
      }
      __syncthreads();
      unsigned long long k0 = skey[r & 1][0], k1 = skey[r & 1][1];
      unsigned long long k2 = skey[r & 1][2], k3 = skey[r & 1][3];
      float4 c0 = scrd[r & 1][0], c1 = scrd[r & 1][1];
      float4 c2 = scrd[r & 1][2], c3 = scrd[r & 1][3];
      if (k1 > k0) { k0 = k1; c0 = c1; }
      if (k2 > k0) { k0 = k2; c0 = c2; }
      if (k3 > k0) { k0 = k3; c0 = c3; }
      lx = c0.x; ly = c0.y; lz = c0.z;
    }
  }
#pragma unroll
  for (int q = 0; q < KS; ++q) {
    const int i = q * 256 + tid;
    outb[3 * i + 0] = sx[q];
    outb[3 * i + 1] = sy[q];
    outb[3 * i + 2] = sz[q];
  }
}

// ---------------- wave-parallel ball query (first ns in-range, ascending) ----
// Done by wave 0 of a block into sidx[]. Ballot + prefix-popcount preserves the
// exact reference semantics (ascending index order, first ns, pad with first,
// 0 if none). Early-exits once ns found (radii are large => usually 1 chunk).
template <int NS>
__device__ __forceinline__ void wave_bq(float qx, float qy, float qz,
                                        const float* __restrict__ src, int Ns,
                                        float r2, int* __restrict__ sidx) {
  const int lane = threadIdx.x;  // caller guarantees threadIdx.x < 64
  int cnt = 0;
  for (int base = 0; base < Ns && cnt < NS; base += 64) {
    const int j = base + lane;
    bool in = false;
    if (j < Ns)
      in = sq3(qx, qy, qz, src[3 * j], src[3 * j + 1], src[3 * j + 2]) < r2;
    const unsigned long long mask = __ballot(in);
    const int pos = cnt + (int)__popcll(mask & ((1ull << lane) - 1ull));
    if (in && pos < NS) sidx[pos] = j;
    cnt += (int)__popcll(mask);
  }
  const int cc = cnt < NS ? cnt : NS;
  const int fill = (cc > 0) ? sidx[0] : 0;
  if (lane >= cc && lane < NS) sidx[lane] = fill;
}

// ---------------- fused ball-query + point-rnn cell ----------------
// One block per (b,m), blockDim == OC. Wave 0 computes the ball query; then all
// threads stage corrT[C][NS] and compute (identical arithmetic to rounds 4-6).
template <int NS, int OC, int CIN>
__global__ __launch_bounds__(OC) void cellf(const float* __restrict__ P1, long p1s,
                                            const float* __restrict__ X1,
                                            const float* __restrict__ P2, long p2s,
                                            const float* __restrict__ S2,
                                            const float* __restrict__ W,
                                            float* __restrict__ Sout,
                                            int M, int Ns, float r2) {
  constexpr int C = OC + CIN + 3;
  const int bm = blockIdx.x;
  const int b = bm / M, m = bm - b * M;
  __shared__ int sidx[NS];
  extern __shared__ float corrT[];  // [C][NS]
  const float* p1 = P1 + (long)b * p1s + (long)m * 3;
  const float p1x = p1[0], p1y = p1[1], p1z = p1[2];
  const float* p2b = P2 + (long)b * p2s;
  if (threadIdx.x < 64) wave_bq<NS>(p1x, p1y, p1z, p2b, Ns, r2, sidx);
  __syncthreads();
  for (int e = threadIdx.x; e < C * NS; e += OC) {
    const int c = e / NS, s = e - c * NS;
    const int j = sidx[s];
    float v;
    if (c < OC) {
      v = S2[((long)b * OC + c) * M + j];
    } else if (CIN > 0 && c < OC + CIN) {
      v = X1[((long)b * CIN + (c - OC)) * M + m];
    } else {
      const int d = c - OC - CIN;
      const float pj = p2b[3 * j + d];
      const float pm = (d == 0) ? p1x : ((d == 1) ? p1y : p1z);
      v = __fsub_rn(pj, pm);
    }
    corrT[e] = v;
  }
  __syncthreads();
  const int o = threadIdx.x;
  const float* w = W + (long)o * C;
  float accs[NS];
#pragma unroll
  for (int s = 0; s < NS; ++s) accs[s] = 0.f;
  for (int c = 0; c < C; ++c) {
    const float wc = w[c];
    const float* cs = corrT + c * NS;
#pragma unroll
    for (int s = 0; s < NS; ++s) accs[s] = fmaf(wc, cs[s], accs[s]);
  }
  float best = accs[0];
#pragma unroll
  for (int s = 1; s < NS; ++s) best = fmaxf(best, accs[s]);
  Sout[((long)b * OC + o) * M + m] = best;
}

// ---------------- fused ball-query + grouped feature max ----------------
// One block per (b,m); queries are a prefix of the source buffer (stride xs).
template <int CH, int NS>
__global__ __launch_bounds__(CH) void qgmaxf(const float* __restrict__ xyz, long xs,
                                             int Mq, int Ms, float r2,
                                             const float* __restrict__ feat,
                                             float* __restrict__ out) {
  const int bm = blockIdx.x;
  const int b = bm / Mq, m = bm - b * Mq;
  __shared__ int sidx[NS];
  const float* xb = xyz + (long)b * xs;
  const float qx = xb[3 * m], qy = xb[3 * m + 1], qz = xb[3 * m + 2];
  if (threadIdx.x < 64) wave_bq<NS>(qx, qy, qz, xb, Ms, r2, sidx);
  __syncthreads();
  const float* fb = feat + ((long)b * CH + threadIdx.x) * Ms;
  float best = -3.0e38f;
#pragma unroll
  for (int s = 0; s < NS; ++s) best = fmaxf(best, fb[sidx[s]]);
  out[((long)b * CH + threadIdx.x) * Mq + m] = best;
}

// ---------------- 3-NN + inverse-distance weights ----------------
// Strict '<' insertion matches lax.top_k tie semantics (lower index first).
__global__ __launch_bounds__(256) void knn3_kernel(const float* __restrict__ unk,
                                                   long ustr, int Mu,
                                                   const float* __restrict__ kn,
                                                   long kstr, int Mk,
                                                   int* __restrict__ oi,
                                                   float* __restrict__ ow, int total) {
  int t = blockIdx.x * 256 + threadIdx.x;
  if (t >= total) return;
  int b = t / Mu, m = t - b * Mu;
  const float* q = unk + (long)b * ustr + (long)m * 3;
  const float qx = q[0], qy = q[1], qz = q[2];
  const float* s = kn + (long)b * kstr;
  float d0 = 3e38f, d1 = 3e38f, d2v = 3e38f;
  int i0 = 0, i1 = 0, i2 = 0;
  for (int j = 0; j < Mk; ++j) {
    float dd = sq3(qx, qy, qz, s[3 * j], s[3 * j + 1], s[3 * j + 2]);
    if (dd < d0) {
      d2v = d1; i2 = i1; d1 = d0; i1 = i0; d0 = dd; i0 = j;
    } else if (dd < d1) {
      d2v = d1; i2 = i1; d1 = dd; i1 = j;
    } else if (dd < d2v) {
      d2v = dd; i2 = j;
    }
  }
  float r0 = 1.0f / __fadd_rn(d0, 1e-8f);
  float r1 = 1.0f / __fadd_rn(d1, 1e-8f);
  float r2 = 1.0f / __fadd_rn(d2v, 1e-8f);
  float sum = __fadd_rn(__fadd_rn(r0, r1), r2);
  ow[t * 3 + 0] = r0 / sum;
  ow[t * 3 + 1] = r1 / sum;
  ow[t * 3 + 2] = r2 / sum;
  oi[t * 3 + 0] = i0;
  oi[t * 3 + 1] = i1;
  oi[t * 3 + 2] = i2;
}

// ---------------- fused interp + concat-copy ----------------
// out (B, Cf+Cg, Md): channels [0,Cf) = 3-NN interp of f (B,Cf,Ms);
// channels [Cf,Cf+Cg) = copy of g (B,Cg,Md).
__global__ __launch_bounds__(256) void interpcat(const float* __restrict__ f, int Cf,
                                                 int Ms, const float* __restrict__ g,
                                                 int Cg, const int* __restrict__ ii,
                                                 const float* __restrict__ iw,
                                                 float* __restrict__ out, int Md,
                                                 int total) {
  int t = blockIdx.x * 256 + threadIdx.x;
  if (t >= total) return;
  const int Ctot = Cf + Cg;
  int m = t % Md;
  int bc = t / Md;
  int c = bc % Ctot;
  int b = bc / Ctot;
  float v;
  if (c < Cf) {
    const int* id = ii + ((long)b * Md + m) * 3;
    const float* w = iw + ((long)b * Md + m) * 3;
    const float* fb = f + ((long)b * Cf + c) * Ms;
    v = __fadd_rn(__fadd_rn(__fmul_rn(fb[id[0]], w[0]), __fmul_rn(fb[id[1]], w[1])),
                  __fmul_rn(fb[id[2]], w[2]));
  } else {
    v = g[((long)b * Cg + (c - Cf)) * Md + m];
  }
  out[t] = v;
}

__global__ __launch_bounds__(256) void copyframe_kernel(const float* __restrict__ xyzs,
                                                        float* __restrict__ frame,
                                                        int total) {
  int t = blockIdx.x * 256 + threadIdx.x;
  if (t >= total) return;
  int b = t / (N0 * 3);
  int rr = t - b * (N0 * 3);
  frame[t] = xyzs[((long)b * LF + (LF / 2 - 1)) * (N0 * 3) + rr];
}

// ---------------- fused interp-to-l1 + 2-layer MLP + frame update ----------------
__global__ __launch_bounds__(64) void mlp_kernel(const float* __restrict__ l2,
                                                 const int* __restrict__ ii,
                                                 const float* __restrict__ iw,
                                                 const float* __restrict__ W1,
                                                 const float* __restrict__ b1,
                                                 const float* __restrict__ W2,
                                                 const float* __restrict__ b2,
                                                 float* __restrict__ frame,
                                                 float* __restrict__ out, int td) {
  const int bn = blockIdx.x;
  const int b = bn / N0, n = bn - b * N0;
  __shared__ float col[448];
  __shared__ float h[64];
  const int* id = ii + (long)bn * 3;
  const float* w = iw + (long)bn * 3;
  const float w0 = w[0], w1 = w[1], w2v = w[2];
  const int i0 = id[0], i1 = id[1], i2 = id[2];
  const float* l2b = l2 + (long)b * 448 * M1;
  for (int c = threadIdx.x; c < 448; c += 64) {
    const float* r = l2b + (long)c * M1;
    col[c] = __fadd_rn(__fadd_rn(__fmul_rn(r[i0], w0), __fmul_rn(r[i1], w1)),
                       __fmul_rn(r[i2], w2v));
  }
  __syncthreads();
  const int o = threadIdx.x;
  const float* wr = W1 + (long)o * 448;
  float acc = b1[o];
  for (int c = 0; c < 448; ++c) acc = fmaf(wr[c], col[c], acc);
  h[o] = fmaxf(acc, 0.0f);
  __syncthreads();
  if (o < 3) {
    const float* w2r = W2 + o * 64;
    float acc2 = b2[o];
    for (int c = 0; c < 64; ++c) acc2 = fmaf(w2r[c], h[c], acc2);
    float nf = frame[(long)bn * 3 + o] + acc2;
    frame[(long)bn * 3 + o] = nf;
    out[(((long)b * 4 + td) * N0 + n) * 3 + o] = nf;
  }
}

extern "C" void kernel_launch(void* const* d_in, const int* in_sizes, int n_in,
                              void* d_out, int out_size, void* d_ws, size_t ws_size,
                              hipStream_t stream) {
  const float* xyzs = (const float*)d_in[0];
  const float* enw[3] = {(const float*)d_in[1], (const float*)d_in[2], (const float*)d_in[3]};
  const float* dew[3] = {(const float*)d_in[4], (const float*)d_in[5], (const float*)d_in[6]};
  const float* mw1 = (const float*)d_in[7];
  const float* mb1 = (const float*)d_in[8];
  const float* mw2 = (const float*)d_in[9];
  const float* mb2 = (const float*)d_in[10];
  float* out = (float*)d_out;

  float* ws = (float*)d_ws;
  size_t off = 0;
  auto alloc = [&](size_t nn) { float* p = ws + off; off += nn; return p; };
  const long st1 = (long)B * M1 * 3;
  float* frame = alloc((size_t)B * N0 * 3);
  float* xyz1e = alloc((size_t)4 * st1);  // encoder timesteps 0..3 (levels 2/3 = prefixes)
  float* xyz1d[2] = {alloc((size_t)st1), alloc((size_t)st1)};  // decoder t=5..7
  float* z1 = alloc((size_t)st1);  // zero "previous positions" (all levels, stride XS)
  float* S1bf[2] = {alloc((size_t)B * O1 * M1), alloc((size_t)B * O1 * M1)};
  float* S2bf[2] = {alloc((size_t)B * O2 * M2), alloc((size_t)B * O2 * M2)};
  float* S3bf[2] = {alloc((size_t)B * O3 * M3), alloc((size_t)B * O3 * M3)};
  float* l3 = alloc((size_t)B * 384 * M2);
  float* l2 = alloc((size_t)B * 448 * M1);
  float* feat2 = alloc((size_t)B * O1 * M2);
  float* feat3 = alloc((size_t)B * O2 * M3);
  float* iw = alloc((size_t)B * N0 * 3);
  int* ii = (int*)alloc((size_t)B * N0 * 3);

  hipMemsetAsync(z1, 0, (size_t)st1 * 4, stream);
  hipMemsetAsync(S1bf[1], 0, (size_t)B * O1 * M1 * 4, stream);
  hipMemsetAsync(S2bf[1], 0, (size_t)B * O2 * M2 * 4, stream);
  hipMemsetAsync(S3bf[1], 0, (size_t)B * O3 * M3 * 4, stream);

  double r;
  r = 4.0 + 1e-6;             const float r2c1 = (float)(r * r);
  r = 2.0 * 4.0 / 4.0 + 1e-6; const float r2q2 = (float)(r * r);
  r = 2.0 * 4.0 + 1e-6;       const float r2c2 = (float)(r * r);
  r = 4.0 * 4.0 / 4.0 + 1e-6; const float r2q3 = (float)(r * r);
  r = 3.0 * 4.0 + 1e-6;       const float r2c3 = (float)(r * r);

  auto grid = [](int total) { return dim3((unsigned)((total + 255) / 256)); };

  // batched encoder FPS (level 1 only; levels 2/3 are prefixes)
  fps6<2048, 1024><<<dim3(B, 4), 256, 0, stream>>>(xyzs, (long)LF * N0 * 3, (long)N0 * 3,
                                                   xyz1e, XS, st1);

  // current-timestep sampled-xyz pointer per t. t=4: frame == xyzs[:,3] bit-exactly,
  // so fps(frame) == encoder t=3's result — reuse it, no dispatch.
  const float* x1_of_t[LF] = {
      xyz1e + 0 * st1, xyz1e + 1 * st1, xyz1e + 2 * st1, xyz1e + 3 * st1,
      xyz1e + 3 * st1, xyz1d[0], xyz1d[1], xyz1d[0]};

  for (int t = 0; t < LF; ++t) {
    const bool enc = t < LF / 2;
    const float* W1 = enc ? enw[0] : dew[0];
    const float* W2 = enc ? enw[1] : dew[1];
    const float* W3 = enc ? enw[2] : dew[2];
    const int cur = t & 1, prev = 1 - cur;  // S-state ping-pong (t=0 reads [1], zeroed)
    if (t == LF / 2)
      copyframe_kernel<<<grid(B * N0 * 3), 256, 0, stream>>>(xyzs, frame, B * N0 * 3);

    const float* x1c = x1_of_t[t];
    const float* x1p = (t == 0) ? z1 : x1_of_t[t - 1];

    if (t > LF / 2)
      fps6<2048, 1024><<<dim3(B, 1), 256, 0, stream>>>(frame, (long)N0 * 3, 0,
                                                       (float*)x1c, XS, 0);
    // ---- level 1 ----
    cellf<NS1, O1, 0><<<B * M1, O1, C1 * NS1 * 4, stream>>>(
        x1c, XS, nullptr, x1p, XS, S1bf[prev], W1, S1bf[cur], M1, M1, r2c1);
    // ---- level 2 (xyz = prefix) ----
    qgmaxf<O1, NSQ><<<B * M2, O1, 0, stream>>>(x1c, XS, M2, M1, r2q2, S1bf[cur], feat2);
    cellf<NS2, O2, O1><<<B * M2, O2, C2 * NS2 * 4, stream>>>(
        x1c, XS, feat2, x1p, XS, S2bf[prev], W2, S2bf[cur], M2, M2, r2c2);
    // ---- level 3 (xyz = prefix) ----
    qgmaxf<O2, NSQ><<<B * M3, O2, 0, stream>>>(x1c, XS, M3, M2, r2q3, S2bf[cur], feat3);
    cellf<NS3, O3, O2><<<B * M3, O3, C3 * NS3 * 4, stream>>>(
        x1c, XS, feat3, x1p, XS, S3bf[prev], W3, S3bf[cur], M3, M3, r2c3);

    if (!enc) {
      const int td = t - LF / 2;
      // l3 = concat([interp(p2<-p3, f3), f2])
      knn3_kernel<<<grid(B * M2), 256, 0, stream>>>(x1c, XS, M2, x1c, XS, M3, ii, iw,
                                                    B * M2);
      interpcat<<<grid(B * 384 * M2), 256, 0, stream>>>(S3bf[cur], O3, M3, S2bf[cur], O2,
                                                        ii, iw, l3, M2, B * 384 * M2);
      // l2 = concat([interp(p1<-p2, l3), f1])
      knn3_kernel<<<grid(B * M1), 256, 0, stream>>>(x1c, XS, M1, x1c, XS, M2, ii, iw,
                                                    B * M1);
      interpcat<<<grid(B * 448 * M1), 256, 0, stream>>>(l3, 384, M2, S1bf[cur], O1, ii,
                                                        iw, l2, M1, B * 448 * M1);
      // l1 = interp(frame<-p1, l2) fused into MLP; frame += motion; emit pred
      knn3_kernel<<<grid(B * N0), 256, 0, stream>>>(frame, (long)N0 * 3, N0, x1c, XS, M1,
                                                    ii, iw, B * N0);
      mlp_kernel<<<B * N0, 64, 0, stream>>>(l2, ii, iw, mw1, mb1, mw2, mb2, frame, out, td);
    }
  }
  (void)in_sizes; (void)n_in; (void)out_size; (void)ws_size;
}

// Round 8
// 5095.895 us; speedup vs baseline: 3.1497x; 1.1237x over previous
//
#include <hip/hip_runtime.h>

// ---------------- problem constants ----------------
static constexpr int B  = 4;
static constexpr int N0 = 2048;
static constexpr int LF = 8;
static constexpr int M1 = 1024, M2 = 512, M3 = 256;
static constexpr int O1 = 64, O2 = 128, O3 = 256;
static constexpr int NS1 = 12, NS2 = 8, NS3 = 4, NSQ = 4;
static constexpr int C1 = 67, C2 = 195, C3 = 387;
// Per-batch stride (floats) for all sampled-xyz arrays. Levels 2/3 are PREFIXES
// of the level-1 FPS output (FPS hierarchical consistency, bit-exact since r6).
static constexpr long XS = 3 * (long)M1;

// Exact float32 squared distance in numpy's op order ((dx^2+dy^2)+dz^2),
// _rn intrinsics forbid FMA contraction (discrete decisions depend on it).
__device__ __forceinline__ float sq3(float ax, float ay, float az,
                                     float bx, float by, float bz) {
  float dx = __fsub_rn(ax, bx), dy = __fsub_rn(ay, by), dz = __fsub_rn(az, bz);
  return __fadd_rn(__fadd_rn(__fmul_rn(dx, dx), __fmul_rn(dy, dy)),
                   __fmul_rn(dz, dz));
}

// u64-key (hi=dist bits, lo=small-idx-favoring) max via DPP. VALU pipe only.
template <int CTRL>
__device__ __forceinline__ void dpp_max_step(unsigned& hi, unsigned& lo) {
  unsigned ohi = (unsigned)__builtin_amdgcn_update_dpp((int)hi, (int)hi, CTRL, 0xf, 0xf, false);
  unsigned olo = (unsigned)__builtin_amdgcn_update_dpp((int)lo, (int)lo, CTRL, 0xf, 0xf, false);
  bool take = (ohi > hi) || (ohi == hi && olo > lo);
  hi = take ? ohi : hi;
  lo = take ? olo : lo;
}

// ---------------- furthest point sampling v7: barrier-free spin sync ----------
// One block (256 thr = 4 waves) per (batch [, timestep]). Rounds 3/5/7 plateaued
// at ~0.6us/iter across different reduce structures => the __syncthreads + LDS
// round-trip (~1000cyc) is the floor. fps7 removes the barrier: each wave's
// lane0 atomically publishes its u64 winner with the iteration TAG packed into
// spare low bits (idx needs 11 bits; bits 12..31 = tag = i+1); all lanes poll
// the 4 slots until every tag matches, then mask+max. DEADLOCK-FREE: every wave
// writes before polling (no circular wait); parity double-buffer + tag make
// overwrite-before-read impossible (w's parity-p write at i+2 follows its poll
// at i+1, which needs x's i+1 write, which follows x's read of parity p at i).
// Tie-break = first occurrence via lo11 = 2047-j, matching jnp.argmax bit-exactly.
template <int N, int NPOINT>
__global__ __launch_bounds__(256, 1) void fps7(const float* __restrict__ pts,
                                               long s1, long s2,
                                               float* __restrict__ out,
                                               long o1, long o2) {
  constexpr int K = N / 256;
  constexpr int KS = NPOINT / 256;
  const float* p = pts + (long)blockIdx.x * s1 + (long)blockIdx.y * s2;
  float* outb = out + (long)blockIdx.x * o1 + (long)blockIdx.y * o2;
  const int tid = threadIdx.x;
  const int lane = tid & 63;
  const int wid = tid >> 6;
  __shared__ float4 sp[N];
  __shared__ unsigned long long skey[2][4];
  float ppx[K], ppy[K], ppz[K], dist[K];
  float sx[KS], sy[KS], sz[KS];
#pragma unroll
  for (int k = 0; k < K; ++k) {
    const int j = k * 256 + tid;
    const float x = p[3 * j + 0], y = p[3 * j + 1], z = p[3 * j + 2];
    ppx[k] = x; ppy[k] = y; ppz[k] = z;
    sp[j] = make_float4(x, y, z, 0.f);
    dist[k] = 1e10f;
  }
  if (tid < 8) ((unsigned long long*)skey)[tid] = 0ull;
  __syncthreads();  // the only barrier: sp[] staging + slot init
  const float4 c00 = sp[0];
  float lx = c00.x, ly = c00.y, lz = c00.z;  // first selected point = index 0
  int i = 0;
#pragma unroll
  for (int q = 0; q < KS; ++q) {
    for (int r = 0; r < 256; ++r, ++i) {
      if (r == tid) { sx[q] = lx; sy[q] = ly; sz[q] = lz; }
      unsigned bhi = 0u, blo = 0u;
#pragma unroll
      for (int k = 0; k < K; ++k) {
        const float d = sq3(ppx[k], ppy[k], ppz[k], lx, ly, lz);
        const float dm = fminf(dist[k], d);
        dist[k] = dm;
        const unsigned h = __float_as_uint(dm);
        const unsigned l = 2047u - (unsigned)(k * 256 + tid);  // 11 bits; bigger = smaller idx
        const bool take = (h > bhi) || (h == bhi && l > blo);
        bhi = take ? h : bhi;
        blo = take ? l : blo;
      }
      // wave64 key reduce on VALU pipe; winner in lane 63
      dpp_max_step<0x111>(bhi, blo);
      dpp_max_step<0x112>(bhi, blo);
      dpp_max_step<0x114>(bhi, blo);
      dpp_max_step<0x118>(bhi, blo);
      dpp_max_step<0x142>(bhi, blo);
      dpp_max_step<0x143>(bhi, blo);
      const unsigned whi = (unsigned)__builtin_amdgcn_readlane((int)bhi, 63);
      const unsigned wlo = (unsigned)__builtin_amdgcn_readlane((int)blo, 63);
      const unsigned tagbits = (unsigned)(i + 1) << 12;
      if (lane == 0)
        __hip_atomic_store(&skey[i & 1][wid],
                           ((unsigned long long)whi << 32) |
                               (unsigned long long)(tagbits | wlo),
                           __ATOMIC_RELAXED, __HIP_MEMORY_SCOPE_WORKGROUP);
      unsigned long long v0, v1, v2, v3;
      for (;;) {
        v0 = __hip_atomic_load(&skey[i & 1][0], __ATOMIC_RELAXED, __HIP_MEMORY_SCOPE_WORKGROUP);
        v1 = __hip_atomic_load(&skey[i & 1][1], __ATOMIC_RELAXED, __HIP_MEMORY_SCOPE_WORKGROUP);
        v2 = __hip_atomic_load(&skey[i & 1][2], __ATOMIC_RELAXED, __HIP_MEMORY_SCOPE_WORKGROUP);
        v3 = __hip_atomic_load(&skey[i & 1][3], __ATOMIC_RELAXED, __HIP_MEMORY_SCOPE_WORKGROUP);
        if (((((unsigned)v0 ^ tagbits) | ((unsigned)v1 ^ tagbits) |
              ((unsigned)v2 ^ tagbits) | ((unsigned)v3 ^ tagbits)) &
             0xFFFFF000u) == 0u)
          break;
      }
      const unsigned long long MASKK = 0xFFFFFFFF000007FFull;  // strip tag bits
      unsigned long long g = v0 & MASKK;
      unsigned long long e = v1 & MASKK; if (e > g) g = e;
      e = v2 & MASKK; if (e > g) g = e;
      e = v3 & MASKK; if (e > g) g = e;
      const int gidx = 2047 - (int)(g & 0x7FFull);
      const float4 c = sp[gidx];  // broadcast ds_read_b128
      lx = c.x; ly = c.y; lz = c.z;
    }
  }
#pragma unroll
  for (int q = 0; q < KS; ++q) {
    const int s = q * 256 + tid;
    outb[3 * s + 0] = sx[q];
    outb[3 * s + 1] = sy[q];
    outb[3 * s + 2] = sz[q];
  }
}

// ---------------- wave-parallel ball query (first ns in-range, ascending) ----
// Executed by one full wave (uniform branch). Ballot + prefix-popcount preserves
// exact reference semantics (ascending order, first ns, pad with first, 0 if none).
template <int NS>
__device__ __forceinline__ void wave_bq(float qx, float qy, float qz,
                                        const float* __restrict__ src, int Ns,
                                        float r2, int* __restrict__ sidx) {
  const int lane = threadIdx.x & 63;
  int cnt = 0;
  for (int base = 0; base < Ns && cnt < NS; base += 64) {
    const int j = base + lane;
    bool in = false;
    if (j < Ns)
      in = sq3(qx, qy, qz, src[3 * j], src[3 * j + 1], src[3 * j + 2]) < r2;
    const unsigned long long mask = __ballot(in);
    const int pos = cnt + (int)__popcll(mask & ((1ull << lane) - 1ull));
    if (in && pos < NS) sidx[pos] = j;
    cnt += (int)__popcll(mask);
  }
  const int cc = cnt < NS ? cnt : NS;
  const int fill = (cc > 0) ? sidx[0] : 0;
  if (lane >= cc && lane < NS) sidx[lane] = fill;
}

// ---------------- fully-fused point-rnn cell ----------------
// One block per (b,m), blockDim == OC. Wave 0: cell ball-query (src = prev xyz).
// Wave 1 (CIN>0): feature ball-query (src = current xyz prefix, radius r2q) —
// the former qgmax kernel, fused; feat kept in LDS (no global round-trip).
template <int NS, int OC, int CIN>
__global__ __launch_bounds__(OC) void cellf(const float* __restrict__ P1, long p1s,
                                            const float* __restrict__ P2, long p2s,
                                            const float* __restrict__ S2,
                                            const float* __restrict__ SF,
                                            const float* __restrict__ W,
                                            float* __restrict__ Sout,
                                            int M, int Ns, float r2,
                                            int Msf, float r2q) {
  constexpr int C = OC + CIN + 3;
  const int bm = blockIdx.x;
  const int b = bm / M, m = bm - b * M;
  __shared__ int sidx[NS];
  __shared__ int sfidx[NSQ];
  __shared__ float featL[CIN > 0 ? CIN : 1];
  extern __shared__ float corrT[];  // [C][NS]
  const int wid = threadIdx.x >> 6;
  const float* p1 = P1 + (long)b * p1s + (long)m * 3;
  const float p1x = p1[0], p1y = p1[1], p1z = p1[2];
  const float* p2b = P2 + (long)b * p2s;
  if (wid == 0) wave_bq<NS>(p1x, p1y, p1z, p2b, Ns, r2, sidx);
  if constexpr (CIN > 0) {
    if (wid == 1) wave_bq<NSQ>(p1x, p1y, p1z, P1 + (long)b * p1s, Msf, r2q, sfidx);
  }
  __syncthreads();
  if constexpr (CIN > 0) {
    if (threadIdx.x < CIN) {
      const float* fb = SF + ((long)b * CIN + threadIdx.x) * Msf;
      float best = -3.0e38f;
#pragma unroll
      for (int s = 0; s < NSQ; ++s) best = fmaxf(best, fb[sfidx[s]]);
      featL[threadIdx.x] = best;
    }
    __syncthreads();
  }
  for (int e = threadIdx.x; e < C * NS; e += OC) {
    const int c = e / NS, s = e - c * NS;
    const int j = sidx[s];
    float v;
    if (c < OC) {
      v = S2[((long)b * OC + c) * M + j];
    } else if (CIN > 0 && c < OC + CIN) {
      v = featL[c - OC];
    } else {
      const int d = c - OC - CIN;
      const float pj = p2b[3 * j + d];
      const float pm = (d == 0) ? p1x : ((d == 1) ? p1y : p1z);
      v = __fsub_rn(pj, pm);
    }
    corrT[e] = v;
  }
  __syncthreads();
  const int o = threadIdx.x;
  const float* w = W + (long)o * C;
  float accs[NS];
#pragma unroll
  for (int s = 0; s < NS; ++s) accs[s] = 0.f;
  for (int c = 0; c < C; ++c) {
    const float wc = w[c];
    const float* cs = corrT + c * NS;
#pragma unroll
    for (int s = 0; s < NS; ++s) accs[s] = fmaf(wc, cs[s], accs[s]);
  }
  float best = accs[0];
#pragma unroll
  for (int s = 1; s < NS; ++s) best = fmaxf(best, accs[s]);
  Sout[((long)b * OC + o) * M + m] = best;
}

// ---------------- merged 3-NN for all three interp levels of a timestep -------
// Segments (block-aligned): [0, B*M2): x2<-x3 ; [B*M2, B*(M2+M1)): x1<-x2 ;
// [B*(M2+M1), +B*N0): frame<-x1. kn is always x1c (stride XS) prefixes.
// Strict '<' insertion matches lax.top_k tie semantics (lower index first).
__global__ __launch_bounds__(256) void knn_all(const float* __restrict__ x1c,
                                               const float* __restrict__ frame,
                                               int* __restrict__ ii2, float* __restrict__ iw2,
                                               int* __restrict__ ii1, float* __restrict__ iw1,
                                               int* __restrict__ ii0, float* __restrict__ iw0) {
  int t = blockIdx.x * 256 + threadIdx.x;
  const float* unk; long ustr; int Mu, Mk; int* oi; float* ow;
  if (t < B * M2) {
    unk = x1c; ustr = XS; Mu = M2; Mk = M3; oi = ii2; ow = iw2;
  } else if (t < B * (M2 + M1)) {
    t -= B * M2;
    unk = x1c; ustr = XS; Mu = M1; Mk = M2; oi = ii1; ow = iw1;
  } else {
    t -= B * (M2 + M1);
    if (t >= B * N0) return;
    unk = frame; ustr = 3L * N0; Mu = N0; Mk = M1; oi = ii0; ow = iw0;
  }
  const int b = t / Mu, m = t - b * Mu;
  const float* q = unk + (long)b * ustr + (long)m * 3;
  const float qx = q[0], qy = q[1], qz = q[2];
  const float* s = x1c + (long)b * XS;
  float d0 = 3e38f, d1 = 3e38f, d2v = 3e38f;
  int i0 = 0, i1 = 0, i2 = 0;
  for (int j = 0; j < Mk; ++j) {
    float dd = sq3(qx, qy, qz, s[3 * j], s[3 * j + 1], s[3 * j + 2]);
    if (dd < d0) {
      d2v = d1; i2 = i1; d1 = d0; i1 = i0; d0 = dd; i0 = j;
    } else if (dd < d1) {
      d2v = d1; i2 = i1; d1 = dd; i1 = j;
    } else if (dd < d2v) {
      d2v = dd; i2 = j;
    }
  }
  float r0 = 1.0f / __fadd_rn(d0, 1e-8f);
  float r1 = 1.0f / __fadd_rn(d1, 1e-8f);
  float r2 = 1.0f / __fadd_rn(d2v, 1e-8f);
  float sum = __fadd_rn(__fadd_rn(r0, r1), r2);
  ow[t * 3 + 0] = r0 / sum;
  ow[t * 3 + 1] = r1 / sum;
  ow[t * 3 + 2] = r2 / sum;
  oi[t * 3 + 0] = i0;
  oi[t * 3 + 1] = i1;
  oi[t * 3 + 2] = i2;
}

// ---------------- fused interp + concat-copy ----------------
__global__ __launch_bounds__(256) void interpcat(const float* __restrict__ f, int Cf,
                                                 int Ms, const float* __restrict__ g,
                                                 int Cg, const int* __restrict__ ii,
                                                 const float* __restrict__ iw,
                                                 float* __restrict__ out, int Md,
                                                 int total) {
  int t = blockIdx.x * 256 + threadIdx.x;
  if (t >= total) return;
  const int Ctot = Cf + Cg;
  int m = t % Md;
  int bc = t / Md;
  int c = bc % Ctot;
  int b = bc / Ctot;
  float v;
  if (c < Cf) {
    const int* id = ii + ((long)b * Md + m) * 3;
    const float* w = iw + ((long)b * Md + m) * 3;
    const float* fb = f + ((long)b * Cf + c) * Ms;
    v = __fadd_rn(__fadd_rn(__fmul_rn(fb[id[0]], w[0]), __fmul_rn(fb[id[1]], w[1])),
                  __fmul_rn(fb[id[2]], w[2]));
  } else {
    v = g[((long)b * Cg + (c - Cf)) * Md + m];
  }
  out[t] = v;
}

__global__ __launch_bounds__(256) void copyframe_kernel(const float* __restrict__ xyzs,
                                                        float* __restrict__ frame,
                                                        int total) {
  int t = blockIdx.x * 256 + threadIdx.x;
  if (t >= total) return;
  int b = t / (N0 * 3);
  int rr = t - b * (N0 * 3);
  frame[t] = xyzs[((long)b * LF + (LF / 2 - 1)) * (N0 * 3) + rr];
}

// ---------------- fused interp-to-l1 + 2-layer MLP + frame update ----------------
__global__ __launch_bounds__(64) void mlp_kernel(const float* __restrict__ l2,
                                                 const int* __restrict__ ii,
                                                 const float* __restrict__ iw,
                                                 const float* __restrict__ W1,
                                                 const float* __restrict__ b1,
                                                 const float* __restrict__ W2,
                                                 const float* __restrict__ b2,
                                                 float* __restrict__ frame,
                                                 float* __restrict__ out, int td) {
  const int bn = blockIdx.x;
  const int b = bn / N0, n = bn - b * N0;
  __shared__ float col[448];
  __shared__ float h[64];
  const int* id = ii + (long)bn * 3;
  const float* w = iw + (long)bn * 3;
  const float w0 = w[0], w1 = w[1], w2v = w[2];
  const int i0 = id[0], i1 = id[1], i2 = id[2];
  const float* l2b = l2 + (long)b * 448 * M1;
  for (int c = threadIdx.x; c < 448; c += 64) {
    const float* r = l2b + (long)c * M1;
    col[c] = __fadd_rn(__fadd_rn(__fmul_rn(r[i0], w0), __fmul_rn(r[i1], w1)),
                       __fmul_rn(r[i2], w2v));
  }
  __syncthreads();
  const int o = threadIdx.x;
  const float* wr = W1 + (long)o * 448;
  float acc = b1[o];
  for (int c = 0; c < 448; ++c) acc = fmaf(wr[c], col[c], acc);
  h[o] = fmaxf(acc, 0.0f);
  __syncthreads();
  if (o < 3) {
    const float* w2r = W2 + o * 64;
    float acc2 = b2[o];
    for (int c = 0; c < 64; ++c) acc2 = fmaf(w2r[c], h[c], acc2);
    float nf = frame[(long)bn * 3 + o] + acc2;
    frame[(long)bn * 3 + o] = nf;
    out[(((long)b * 4 + td) * N0 + n) * 3 + o] = nf;
  }
}

extern "C" void kernel_launch(void* const* d_in, const int* in_sizes, int n_in,
                              void* d_out, int out_size, void* d_ws, size_t ws_size,
                              hipStream_t stream) {
  const float* xyzs = (const float*)d_in[0];
  const float* enw[3] = {(const float*)d_in[1], (const float*)d_in[2], (const float*)d_in[3]};
  const float* dew[3] = {(const float*)d_in[4], (const float*)d_in[5], (const float*)d_in[6]};
  const float* mw1 = (const float*)d_in[7];
  const float* mb1 = (const float*)d_in[8];
  const float* mw2 = (const float*)d_in[9];
  const float* mb2 = (const float*)d_in[10];
  float* out = (float*)d_out;

  float* ws = (float*)d_ws;
  size_t off = 0;
  auto alloc = [&](size_t nn) { float* p = ws + off; off += nn; return p; };
  const long st1 = (long)B * M1 * 3;
  float* frame = alloc((size_t)B * N0 * 3);
  float* xyz1e = alloc((size_t)4 * st1);  // encoder t=0..3 (levels 2/3 = prefixes)
  float* xyz1d[2] = {alloc((size_t)st1), alloc((size_t)st1)};  // decoder t=5..7
  float* z1 = alloc((size_t)st1);  // zero "previous positions"
  float* S1bf[2] = {alloc((size_t)B * O1 * M1), alloc((size_t)B * O1 * M1)};
  float* S2bf[2] = {alloc((size_t)B * O2 * M2), alloc((size_t)B * O2 * M2)};
  float* S3bf[2] = {alloc((size_t)B * O3 * M3), alloc((size_t)B * O3 * M3)};
  float* l3 = alloc((size_t)B * 384 * M2);
  float* l2 = alloc((size_t)B * 448 * M1);
  float* iw0 = alloc((size_t)B * N0 * 3);
  int* ii0 = (int*)alloc((size_t)B * N0 * 3);
  float* iw1 = alloc((size_t)B * M1 * 3);
  int* ii1 = (int*)alloc((size_t)B * M1 * 3);
  float* iw2 = alloc((size_t)B * M2 * 3);
  int* ii2 = (int*)alloc((size_t)B * M2 * 3);

  hipMemsetAsync(z1, 0, (size_t)st1 * 4, stream);
  hipMemsetAsync(S1bf[1], 0, (size_t)B * O1 * M1 * 4, stream);
  hipMemsetAsync(S2bf[1], 0, (size_t)B * O2 * M2 * 4, stream);
  hipMemsetAsync(S3bf[1], 0, (size_t)B * O3 * M3 * 4, stream);

  double r;
  r = 4.0 + 1e-6;             const float r2c1 = (float)(r * r);
  r = 2.0 * 4.0 / 4.0 + 1e-6; const float r2q2 = (float)(r * r);
  r = 2.0 * 4.0 + 1e-6;       const float r2c2 = (float)(r * r);
  r = 4.0 * 4.0 / 4.0 + 1e-6; const float r2q3 = (float)(r * r);
  r = 3.0 * 4.0 + 1e-6;       const float r2c3 = (float)(r * r);

  auto grid = [](int total) { return dim3((unsigned)((total + 255) / 256)); };

  // batched encoder FPS (level 1 only; levels 2/3 are prefixes)
  fps7<2048, 1024><<<dim3(B, 4), 256, 0, stream>>>(xyzs, (long)LF * N0 * 3, (long)N0 * 3,
                                                   xyz1e, XS, st1);

  // t=4: frame == xyzs[:,3] bit-exactly => fps(frame) == encoder t=3's result.
  const float* x1_of_t[LF] = {
      xyz1e + 0 * st1, xyz1e + 1 * st1, xyz1e + 2 * st1, xyz1e + 3 * st1,
      xyz1e + 3 * st1, xyz1d[0], xyz1d[1], xyz1d[0]};

  for (int t = 0; t < LF; ++t) {
    const bool enc = t < LF / 2;
    const float* W1 = enc ? enw[0] : dew[0];
    const float* W2 = enc ? enw[1] : dew[1];
    const float* W3 = enc ? enw[2] : dew[2];
    const int cur = t & 1, prev = 1 - cur;  // S-state ping-pong (t=0 reads [1], zeroed)
    if (t == LF / 2)
      copyframe_kernel<<<grid(B * N0 * 3), 256, 0, stream>>>(xyzs, frame, B * N0 * 3);

    const float* x1c = x1_of_t[t];
    const float* x1p = (t == 0) ? z1 : x1_of_t[t - 1];

    if (t > LF / 2)
      fps7<2048, 1024><<<dim3(B, 1), 256, 0, stream>>>(frame, (long)N0 * 3, 0,
                                                       (float*)x1c, XS, 0);
    if (!enc)  // all three 3-NN levels in one dispatch, off the critical tail
      knn_all<<<dim3(56), 256, 0, stream>>>(x1c, frame, ii2, iw2, ii1, iw1, ii0, iw0);

    // ---- level 1 ----
    cellf<NS1, O1, 0><<<B * M1, O1, C1 * NS1 * 4, stream>>>(
        x1c, XS, x1p, XS, S1bf[prev], nullptr, W1, S1bf[cur], M1, M1, r2c1, 0, 0.f);
    // ---- level 2 (xyz = prefix; qgmax fused as wave-1 ball query) ----
    cellf<NS2, O2, O1><<<B * M2, O2, C2 * NS2 * 4, stream>>>(
        x1c, XS, x1p, XS, S2bf[prev], S1bf[cur], W2, S2bf[cur], M2, M2, r2c2, M1, r2q2);
    // ---- level 3 ----
    cellf<NS3, O3, O2><<<B * M3, O3, C3 * NS3 * 4, stream>>>(
        x1c, XS, x1p, XS, S3bf[prev], S2bf[cur], W3, S3bf[cur], M3, M3, r2c3, M2, r2q3);

    if (!enc) {
      const int td = t - LF / 2;
      interpcat<<<grid(B * 384 * M2), 256, 0, stream>>>(S3bf[cur], O3, M3, S2bf[cur], O2,
                                                        ii2, iw2, l3, M2, B * 384 * M2);
      interpcat<<<grid(B * 448 * M1), 256, 0, stream>>>(l3, 384, M2, S1bf[cur], O1, ii1,
                                                        iw1, l2, M1, B * 448 * M1);
      mlp_kernel<<<B * N0, 64, 0, stream>>>(l2, ii0, iw0, mw1, mb1, mw2, mb2, frame, out,
                                            td);
    }
  }
  (void)in_sizes; (void)n_in; (void)out_size; (void)ws_size;
}